// Round 6
// baseline (316.639 us; speedup 1.0000x reference)
//
#include <hip/hip_runtime.h>

typedef unsigned short u16;
typedef u16 u16x8 __attribute__((ext_vector_type(8)));
typedef __bf16 bf16x8 __attribute__((ext_vector_type(8)));
typedef float f32x4 __attribute__((ext_vector_type(4)));

constexpr int NT   = 4096;   // tokens = B*T
constexpr int HD   = 512;    // hidden
constexpr int ID   = 1024;   // inter
constexpr int NEXP = 8;
constexpr int ROWCAP = 13312;   // 4096 shared + 9216 padded routed (104*128)
constexpr int MAXRB  = 104;

// ---- workspace layout (bytes) ----
constexpr size_t OFF_XB   = 0;
constexpr size_t OFF_WGT  = OFF_XB   + (size_t)NT*HD*2;
constexpr size_t OFF_WUT  = OFF_WGT  + (size_t)NEXP*ID*HD*2;
constexpr size_t OFF_WDT  = OFF_WUT  + (size_t)NEXP*ID*HD*2;
constexpr size_t OFF_SGT  = OFF_WDT  + (size_t)NEXP*HD*ID*2;
constexpr size_t OFF_SUT  = OFF_SGT  + (size_t)ID*HD*2;
constexpr size_t OFF_SDT  = OFF_SUT  + (size_t)ID*HD*2;
constexpr size_t OFF_HBUF = OFF_SDT  + (size_t)HD*ID*2;
constexpr size_t OFF_TOK  = OFF_HBUF + (size_t)ROWCAP*ID*2;
constexpr size_t OFF_WGTW = OFF_TOK  + (size_t)ROWCAP*4;
constexpr size_t OFF_TI   = OFF_WGTW + (size_t)ROWCAP*4;
constexpr size_t OFF_TW   = OFF_TI   + (size_t)NT*16;
constexpr size_t OFF_META = OFF_TW   + (size_t)NT*8;
constexpr size_t WS_NEED  = OFF_META + 512;
// meta ints: [0..8)=cnt, [8..17)=segoff (segoff[8]=meta[16]), [17]=nrb, [18..122)=rbe

__device__ __forceinline__ u16 f2bf(float f){
  unsigned int u = __float_as_uint(f);
  u += 0x7fffu + ((u >> 16) & 1u);
  return (u16)(u >> 16);
}

#define AS1C(p) ((const __attribute__((address_space(1))) void*)(p))
#define AS3(p)  ((__attribute__((address_space(3))) void*)(p))
__device__ __forceinline__ void gld16(const void* g, void* l){
  __builtin_amdgcn_global_load_lds(AS1C(g), AS3(l), 16, 0, 0);
}

// ---------------- weight transpose+convert: fp32 [R][C] -> bf16 [C][R] ----------------
__global__ __launch_bounds__(256) void transpose_convert_kernel(
    const float* __restrict__ Wg, const float* __restrict__ Wu, const float* __restrict__ Wd,
    const float* __restrict__ Sg, const float* __restrict__ Su, const float* __restrict__ Sd,
    u16* __restrict__ WgT, u16* __restrict__ WuT, u16* __restrict__ WdT,
    u16* __restrict__ SgT, u16* __restrict__ SuT, u16* __restrict__ SdT)
{
  int b = blockIdx.x;
  const float* src; u16* dst; int R, C, t;
  if (b < 4096)      { int e=b>>9; t=b&511; src=Wg+(size_t)e*HD*ID; dst=WgT+(size_t)e*ID*HD; R=HD; C=ID; }
  else if (b < 8192) { b-=4096; int e=b>>9; t=b&511; src=Wu+(size_t)e*HD*ID; dst=WuT+(size_t)e*ID*HD; R=HD; C=ID; }
  else if (b < 12288){ b-=8192; int e=b>>9; t=b&511; src=Wd+(size_t)e*ID*HD; dst=WdT+(size_t)e*HD*ID; R=ID; C=HD; }
  else if (b < 12800){ t=b-12288; src=Sg; dst=SgT; R=HD; C=ID; }
  else if (b < 13312){ t=b-12800; src=Su; dst=SuT; R=HD; C=ID; }
  else               { t=b-13312; src=Sd; dst=SdT; R=ID; C=HD; }
  const int tc = C >> 5;
  const int r0 = (t / tc) << 5, c0 = (t % tc) << 5;
  __shared__ float tile[32][33];
  const int tx = threadIdx.x & 31, ty = threadIdx.x >> 5;
  #pragma unroll
  for (int j=0;j<4;j++) tile[ty+j*8][tx] = src[(size_t)(r0+ty+j*8)*C + c0+tx];
  __syncthreads();
  #pragma unroll
  for (int j=0;j<4;j++) dst[(size_t)(c0+ty+j*8)*R + r0+tx] = f2bf(tile[tx][ty+j*8]);
}

// ---------------- router: fp32 scores, top-2, bf16 x conversion ----------------
__global__ __launch_bounds__(256) void router_kernel(
    const float* __restrict__ x, const float* __restrict__ rw,
    u16* __restrict__ xb, int* __restrict__ tok, float* __restrict__ wgt,
    int4* __restrict__ tokinfo, float2* __restrict__ tw, int* __restrict__ cnt)
{
  const int wave = threadIdx.x >> 6, lane = threadIdx.x & 63;
  const int n = blockIdx.x*4 + wave;
  const float4 xv0 = *(const float4*)(x + (size_t)n*HD + lane*8);
  const float4 xv1 = *(const float4*)(x + (size_t)n*HD + lane*8 + 4);
  u16x8 xs;
  xs[0]=f2bf(xv0.x); xs[1]=f2bf(xv0.y); xs[2]=f2bf(xv0.z); xs[3]=f2bf(xv0.w);
  xs[4]=f2bf(xv1.x); xs[5]=f2bf(xv1.y); xs[6]=f2bf(xv1.z); xs[7]=f2bf(xv1.w);
  *(u16x8*)(xb + (size_t)n*HD + lane*8) = xs;
  const float xa[8] = {xv0.x,xv0.y,xv0.z,xv0.w,xv1.x,xv1.y,xv1.z,xv1.w};
  float p[8] = {0,0,0,0,0,0,0,0};
  const float4* rp = (const float4*)(rw + (size_t)lane*8*NEXP);
  #pragma unroll
  for (int j=0;j<8;j++){
    float4 r0 = rp[j*2], r1 = rp[j*2+1];
    p[0]+=xa[j]*r0.x; p[1]+=xa[j]*r0.y; p[2]+=xa[j]*r0.z; p[3]+=xa[j]*r0.w;
    p[4]+=xa[j]*r1.x; p[5]+=xa[j]*r1.y; p[6]+=xa[j]*r1.z; p[7]+=xa[j]*r1.w;
  }
  #pragma unroll
  for (int m=1;m<64;m<<=1){
    #pragma unroll
    for (int e=0;e<8;e++) p[e] += __shfl_xor(p[e], m, 64);
  }
  if (lane == 0){
    int e0 = 0; float s0 = p[0];
    #pragma unroll
    for (int e=1;e<8;e++) if (p[e] > s0){ s0 = p[e]; e0 = e; }
    int e1 = -1; float s1 = -3.4e38f;
    #pragma unroll
    for (int e=0;e<8;e++) if (e != e0 && p[e] > s1){ s1 = p[e]; e1 = e; }
    const float w0 = 1.f / (1.f + expf(s1 - s0));
    const int p0 = atomicAdd(cnt + e0, 1);
    const int p1 = atomicAdd(cnt + e1, 1);
    tokinfo[n] = make_int4(e0, e1, p0, p1);
    tw[n] = make_float2(w0, 1.f - w0);
    tok[n] = n;       // shared segment (rows 0..NT): identity
    wgt[n] = 1.0f;
  }
}

// ---------------- segment offsets, rb->expert table, pad init, scatter ----------------
__global__ __launch_bounds__(256) void build_lists_kernel(
    int* __restrict__ meta, int* __restrict__ tok, float* __restrict__ wgt,
    const int4* __restrict__ tokinfo, const float2* __restrict__ tw)
{
  __shared__ int s_off[9];
  const int t = threadIdx.x;
  if (t == 0){
    int off = NT;
    for (int e=0;e<NEXP;e++){ meta[8+e] = off; off += ((meta[e]+127)>>7)<<7; }
    meta[16] = off;
    meta[17] = off >> 7;                       // nrb
    for (int rb=0; rb<32; rb++) meta[18+rb] = 8;   // shared segment
    for (int e=0;e<NEXP;e++){
      int b0 = meta[8+e] >> 7, b1 = meta[9+e] >> 7;
      for (int rb=b0; rb<b1; rb++) meta[18+rb] = e;
    }
    for (int e=0;e<9;e++) s_off[e] = meta[8+e];
  }
  __syncthreads();
  const int end = s_off[8];
  for (int i = NT + t; i < end; i += 256) tok[i] = -1;
  __syncthreads();
  for (int n = t; n < NT; n += 256){
    int4 ti = tokinfo[n];
    float2 w = tw[n];
    int a0 = s_off[ti.x] + ti.z; tok[a0] = n; wgt[a0] = w.x;
    int a1 = s_off[ti.y] + ti.w; tok[a1] = n; wgt[a1] = w.y;
  }
}

// ---------------- GEMM1: h = silu(x@Wg) * (x@Wu), gathered rows, bf16 out ----------------
__global__ __launch_bounds__(256,2) void gemm1_kernel(
    const u16* __restrict__ xb, const u16* __restrict__ WgT, const u16* __restrict__ WuT,
    const u16* __restrict__ SgT, const u16* __restrict__ SuT,
    const int* __restrict__ tok, const int* __restrict__ meta, u16* __restrict__ Hbuf)
{
  const int rb = blockIdx.y;
  if (rb >= meta[17]) return;
  const int e = meta[18+rb];
  const u16* __restrict__ Bg = (e < NEXP) ? (WgT + (size_t)e*ID*HD) : SgT;
  const u16* __restrict__ Bu = (e < NEXP) ? (WuT + (size_t)e*ID*HD) : SuT;
  const int n0 = blockIdx.x << 7;
  const int a0 = rb << 7;
  __shared__ u16 smem[24576];                 // 48 KiB: A | G | U tiles (128 x 64 bf16 each)
  u16* sA = smem; u16* sG = smem + 8192; u16* sU = smem + 16384;
  const int tid = threadIdx.x;
  const int wave = tid >> 6, lane = tid & 63;
  const int wr = wave >> 1, wc = wave & 1;
  const int kb = lane & 7;
  int trowA[4];
  #pragma unroll
  for (int r=0;r<4;r++){
    int row = (wave*4+r)*8 + (lane>>3);
    int tt = tok[a0 + row];
    trowA[r] = (tt < 0) ? 0 : tt;             // pad rows read row 0 (discarded later)
  }
  f32x4 accG[4][4], accU[4][4];
  const f32x4 zz = {0.f,0.f,0.f,0.f};
  #pragma unroll
  for (int mi=0;mi<4;mi++)
    #pragma unroll
    for (int ni=0;ni<4;ni++){ accG[mi][ni] = zz; accU[mi][ni] = zz; }

  for (int it=0; it<HD/64; ++it){
    const int k0 = it*64;
    #pragma unroll
    for (int r=0;r<4;r++){
      const int chunk = wave*4 + r;
      const int row = chunk*8 + (lane>>3);
      gld16(xb + (size_t)trowA[r]*HD + k0 + kb*8, sA + chunk*512);
      gld16(Bg + (size_t)(n0+row)*HD + k0 + kb*8, sG + chunk*512);
      gld16(Bu + (size_t)(n0+row)*HD + k0 + kb*8, sU + chunk*512);
    }
    __syncthreads();
    #pragma unroll
    for (int ks=0; ks<2; ++ks){
      const int ko = ks*32 + ((lane>>4)<<3);
      bf16x8 av[4];
      #pragma unroll
      for (int mi=0;mi<4;mi++)
        av[mi] = *(const bf16x8*)(sA + (wr*64+mi*16+(lane&15))*64 + ko);
      #pragma unroll
      for (int ni=0;ni<4;ni++){
        bf16x8 gv = *(const bf16x8*)(sG + (wc*64+ni*16+(lane&15))*64 + ko);
        bf16x8 uv = *(const bf16x8*)(sU + (wc*64+ni*16+(lane&15))*64 + ko);
        #pragma unroll
        for (int mi=0;mi<4;mi++){
          accG[mi][ni] = __builtin_amdgcn_mfma_f32_16x16x32_bf16(av[mi], gv, accG[mi][ni], 0,0,0);
          accU[mi][ni] = __builtin_amdgcn_mfma_f32_16x16x32_bf16(av[mi], uv, accU[mi][ni], 0,0,0);
        }
      }
    }
    __syncthreads();
  }
  // epilogue: silu(g)*u -> bf16 tile in LDS -> coalesced store
  u16* hT = smem;                              // 128x128 bf16 = 32 KiB
  #pragma unroll
  for (int mi=0;mi<4;mi++){
    #pragma unroll
    for (int ni=0;ni<4;ni++){
      const int col = wc*64 + ni*16 + (lane&15);
      #pragma unroll
      for (int j=0;j<4;j++){
        const int row = wr*64 + mi*16 + ((lane>>4)<<2) + j;
        const float g = accG[mi][ni][j], u = accU[mi][ni][j];
        const float h = (g / (1.f + __expf(-g))) * u;
        hT[row*128 + col] = f2bf(h);
      }
    }
  }
  __syncthreads();
  #pragma unroll
  for (int r=0;r<8;r++){
    const int o = r*2048 + tid*8;
    const int row = o >> 7, col = o & 127;
    *(u16x8*)(Hbuf + (size_t)(a0+row)*ID + n0 + col) = *(const u16x8*)(hT + o);
  }
}

// ---------------- GEMM2: y = h @ Wd, weighted atomic scatter-add into out ----------------
__global__ __launch_bounds__(256,2) void gemm2_kernel(
    const u16* __restrict__ Hbuf, const u16* __restrict__ WdT, const u16* __restrict__ SdT,
    const int* __restrict__ tok, const float* __restrict__ wgt,
    const int* __restrict__ meta, float* __restrict__ out)
{
  const int rb = blockIdx.y;
  if (rb >= meta[17]) return;
  const int e = meta[18+rb];
  const u16* __restrict__ Bd = (e < NEXP) ? (WdT + (size_t)e*HD*ID) : SdT;
  const int n0 = blockIdx.x << 7;
  const int a0 = rb << 7;
  __shared__ u16 smem[16384];                  // 32 KiB: A | B tiles
  u16* sA = smem; u16* sB = smem + 8192;
  const int tid = threadIdx.x;
  const int wave = tid >> 6, lane = tid & 63;
  const int wr = wave >> 1, wc = wave & 1;
  const int kb = lane & 7;
  f32x4 acc[4][4];
  const f32x4 zz = {0.f,0.f,0.f,0.f};
  #pragma unroll
  for (int mi=0;mi<4;mi++)
    #pragma unroll
    for (int ni=0;ni<4;ni++) acc[mi][ni] = zz;

  for (int it=0; it<ID/64; ++it){
    const int k0 = it*64;
    #pragma unroll
    for (int r=0;r<4;r++){
      const int chunk = wave*4 + r;
      const int row = chunk*8 + (lane>>3);
      gld16(Hbuf + (size_t)(a0+row)*ID + k0 + kb*8, sA + chunk*512);
      gld16(Bd   + (size_t)(n0+row)*ID + k0 + kb*8, sB + chunk*512);
    }
    __syncthreads();
    #pragma unroll
    for (int ks=0; ks<2; ++ks){
      const int ko = ks*32 + ((lane>>4)<<3);
      bf16x8 av[4];
      #pragma unroll
      for (int mi=0;mi<4;mi++)
        av[mi] = *(const bf16x8*)(sA + (wr*64+mi*16+(lane&15))*64 + ko);
      #pragma unroll
      for (int ni=0;ni<4;ni++){
        bf16x8 bv = *(const bf16x8*)(sB + (wc*64+ni*16+(lane&15))*64 + ko);
        #pragma unroll
        for (int mi=0;mi<4;mi++)
          acc[mi][ni] = __builtin_amdgcn_mfma_f32_16x16x32_bf16(av[mi], bv, acc[mi][ni], 0,0,0);
      }
    }
    __syncthreads();
  }
  #pragma unroll
  for (int mi=0;mi<4;mi++){
    #pragma unroll
    for (int j=0;j<4;j++){
      const int row = wr*64 + mi*16 + ((lane>>4)<<2) + j;
      const int a = a0 + row;
      const int t = tok[a];
      if (t < 0) continue;
      const float w = wgt[a];
      float* orow = out + (size_t)t*HD + n0 + wc*64 + (lane&15);
      #pragma unroll
      for (int ni=0;ni<4;ni++)
        atomicAdd(orow + ni*16, w * acc[mi][ni][j]);
    }
  }
}

extern "C" void kernel_launch(void* const* d_in, const int* in_sizes, int n_in,
                              void* d_out, int out_size, void* d_ws, size_t ws_size,
                              hipStream_t stream)
{
  (void)in_sizes; (void)n_in;
  if (ws_size < WS_NEED) return;
  const float* x  = (const float*)d_in[0];
  const float* rw = (const float*)d_in[1];
  const float* Wg = (const float*)d_in[2];
  const float* Wu = (const float*)d_in[3];
  const float* Wd = (const float*)d_in[4];
  const float* Sg = (const float*)d_in[5];
  const float* Su = (const float*)d_in[6];
  const float* Sd = (const float*)d_in[7];
  float* out = (float*)d_out;
  char* ws = (char*)d_ws;
  u16*   xb   = (u16*)  (ws + OFF_XB);
  u16*   WgT  = (u16*)  (ws + OFF_WGT);
  u16*   WuT  = (u16*)  (ws + OFF_WUT);
  u16*   WdT  = (u16*)  (ws + OFF_WDT);
  u16*   SgT  = (u16*)  (ws + OFF_SGT);
  u16*   SuT  = (u16*)  (ws + OFF_SUT);
  u16*   SdT  = (u16*)  (ws + OFF_SDT);
  u16*   Hbuf = (u16*)  (ws + OFF_HBUF);
  int*   tok  = (int*)  (ws + OFF_TOK);
  float* wgt  = (float*)(ws + OFF_WGTW);
  int4*  ti   = (int4*) (ws + OFF_TI);
  float2* tw  = (float2*)(ws + OFF_TW);
  int*   meta = (int*)  (ws + OFF_META);

  hipMemsetAsync(out, 0, (size_t)out_size * sizeof(float), stream);
  hipMemsetAsync(meta, 0, 32, stream);   // cnt[8]

  transpose_convert_kernel<<<13824, 256, 0, stream>>>(Wg,Wu,Wd,Sg,Su,Sd, WgT,WuT,WdT,SgT,SuT,SdT);
  router_kernel<<<NT/4, 256, 0, stream>>>(x, rw, xb, tok, wgt, ti, tw, meta);
  build_lists_kernel<<<1, 256, 0, stream>>>(meta, tok, wgt, ti, tw);
  gemm1_kernel<<<dim3(ID/128, MAXRB), 256, 0, stream>>>(xb, WgT, WuT, SgT, SuT, tok, meta, Hbuf);
  gemm2_kernel<<<dim3(HD/128, MAXRB), 256, 0, stream>>>(Hbuf, WdT, SdT, tok, wgt, meta, out);
}

// Round 7
// 243.934 us; speedup vs baseline: 1.2981x; 1.2981x over previous
//
#include <hip/hip_runtime.h>

typedef unsigned short u16;
typedef u16 u16x8 __attribute__((ext_vector_type(8)));
typedef __bf16 bf16x8 __attribute__((ext_vector_type(8)));
typedef float f32x4 __attribute__((ext_vector_type(4)));

constexpr int NT   = 4096;   // tokens = B*T
constexpr int HD   = 512;    // hidden
constexpr int ID   = 1024;   // inter
constexpr int NEXP = 8;
constexpr int ROWCAP = 13312;   // 4096 shared + 9216 padded routed (104*128)
constexpr int MAXRB  = 104;

// ---- workspace layout (bytes) ----
constexpr size_t OFF_XB   = 0;
constexpr size_t OFF_WGT  = OFF_XB   + (size_t)NT*HD*2;
constexpr size_t OFF_WUT  = OFF_WGT  + (size_t)NEXP*ID*HD*2;
constexpr size_t OFF_WDT  = OFF_WUT  + (size_t)NEXP*ID*HD*2;
constexpr size_t OFF_SGT  = OFF_WDT  + (size_t)NEXP*HD*ID*2;
constexpr size_t OFF_SUT  = OFF_SGT  + (size_t)ID*HD*2;
constexpr size_t OFF_SDT  = OFF_SUT  + (size_t)ID*HD*2;
constexpr size_t OFF_HBUF = OFF_SDT  + (size_t)HD*ID*2;
constexpr size_t OFF_TOK  = OFF_HBUF + (size_t)ROWCAP*ID*2;
constexpr size_t OFF_WGTW = OFF_TOK  + (size_t)ROWCAP*4;
constexpr size_t OFF_TI   = OFF_WGTW + (size_t)ROWCAP*4;
constexpr size_t OFF_TW   = OFF_TI   + (size_t)NT*16;
constexpr size_t OFF_META = OFF_TW   + (size_t)NT*8;
constexpr size_t WS_NEED  = OFF_META + 2048;
// meta int layout:
//   [e*16]           e=0..7   : padded expert counters (64B apart -> no shared cache line)
//   [200..208]                : segoff[0..8] (segoff[8] = total padded rows at [208])
//   [210]                     : nrb
//   [212..316)                : rbe (row-block -> expert table)

__device__ __forceinline__ u16 f2bf(float f){
  unsigned int u = __float_as_uint(f);
  u += 0x7fffu + ((u >> 16) & 1u);
  return (u16)(u >> 16);
}

#define AS1C(p) ((const __attribute__((address_space(1))) void*)(p))
#define AS3(p)  ((__attribute__((address_space(3))) void*)(p))
__device__ __forceinline__ void gld16(const void* g, void* l){
  __builtin_amdgcn_global_load_lds(AS1C(g), AS3(l), 16, 0, 0);
}

// ---------------- weight transpose+convert: fp32 [R][C] -> bf16 [C][R] ----------------
__global__ __launch_bounds__(256) void transpose_convert_kernel(
    const float* __restrict__ Wg, const float* __restrict__ Wu, const float* __restrict__ Wd,
    const float* __restrict__ Sg, const float* __restrict__ Su, const float* __restrict__ Sd,
    u16* __restrict__ WgT, u16* __restrict__ WuT, u16* __restrict__ WdT,
    u16* __restrict__ SgT, u16* __restrict__ SuT, u16* __restrict__ SdT)
{
  int b = blockIdx.x;
  const float* src; u16* dst; int R, C, t;
  if (b < 4096)      { int e=b>>9; t=b&511; src=Wg+(size_t)e*HD*ID; dst=WgT+(size_t)e*ID*HD; R=HD; C=ID; }
  else if (b < 8192) { b-=4096; int e=b>>9; t=b&511; src=Wu+(size_t)e*HD*ID; dst=WuT+(size_t)e*ID*HD; R=HD; C=ID; }
  else if (b < 12288){ b-=8192; int e=b>>9; t=b&511; src=Wd+(size_t)e*ID*HD; dst=WdT+(size_t)e*HD*ID; R=ID; C=HD; }
  else if (b < 12800){ t=b-12288; src=Sg; dst=SgT; R=HD; C=ID; }
  else if (b < 13312){ t=b-12800; src=Su; dst=SuT; R=HD; C=ID; }
  else               { t=b-13312; src=Sd; dst=SdT; R=ID; C=HD; }
  const int tc = C >> 5;
  const int r0 = (t / tc) << 5, c0 = (t % tc) << 5;
  __shared__ float tile[32][33];
  const int tx = threadIdx.x & 31, ty = threadIdx.x >> 5;
  #pragma unroll
  for (int j=0;j<4;j++) tile[ty+j*8][tx] = src[(size_t)(r0+ty+j*8)*C + c0+tx];
  __syncthreads();
  #pragma unroll
  for (int j=0;j<4;j++) dst[(size_t)(c0+ty+j*8)*R + r0+tx] = f2bf(tile[tx][ty+j*8]);
}

// ---------------- router: per-block aggregated counting (fix 8192-same-line atomics) ----------------
constexpr int RTOK = 32;   // tokens per block (8 per wave)
__global__ __launch_bounds__(256) void router_kernel(
    const float* __restrict__ x, const float* __restrict__ rw,
    u16* __restrict__ xb, int* __restrict__ tok, float* __restrict__ wgt,
    int4* __restrict__ tokinfo, float2* __restrict__ tw, int* __restrict__ cnt)
{
  const int wave = threadIdx.x >> 6, lane = threadIdx.x & 63;
  __shared__ int h[8];
  __shared__ int basev[8];
  __shared__ int s_e0[RTOK], s_e1[RTOK], s_l0[RTOK], s_l1[RTOK];
  __shared__ float s_w0[RTOK];
  if (threadIdx.x < 8) h[threadIdx.x] = 0;
  __syncthreads();

  #pragma unroll
  for (int t=0; t<RTOK/4; ++t){
    const int slot = wave*(RTOK/4) + t;
    const int n = blockIdx.x*RTOK + slot;
    const float4 xv0 = *(const float4*)(x + (size_t)n*HD + lane*8);
    const float4 xv1 = *(const float4*)(x + (size_t)n*HD + lane*8 + 4);
    u16x8 xs;
    xs[0]=f2bf(xv0.x); xs[1]=f2bf(xv0.y); xs[2]=f2bf(xv0.z); xs[3]=f2bf(xv0.w);
    xs[4]=f2bf(xv1.x); xs[5]=f2bf(xv1.y); xs[6]=f2bf(xv1.z); xs[7]=f2bf(xv1.w);
    *(u16x8*)(xb + (size_t)n*HD + lane*8) = xs;
    const float xa[8] = {xv0.x,xv0.y,xv0.z,xv0.w,xv1.x,xv1.y,xv1.z,xv1.w};
    float p[8] = {0,0,0,0,0,0,0,0};
    const float4* rp = (const float4*)(rw + (size_t)lane*8*NEXP);
    #pragma unroll
    for (int j=0;j<8;j++){
      float4 r0 = rp[j*2], r1 = rp[j*2+1];
      p[0]+=xa[j]*r0.x; p[1]+=xa[j]*r0.y; p[2]+=xa[j]*r0.z; p[3]+=xa[j]*r0.w;
      p[4]+=xa[j]*r1.x; p[5]+=xa[j]*r1.y; p[6]+=xa[j]*r1.z; p[7]+=xa[j]*r1.w;
    }
    #pragma unroll
    for (int m=1;m<64;m<<=1){
      #pragma unroll
      for (int e=0;e<8;e++) p[e] += __shfl_xor(p[e], m, 64);
    }
    if (lane == 0){
      int e0 = 0; float s0 = p[0];
      #pragma unroll
      for (int e=1;e<8;e++) if (p[e] > s0){ s0 = p[e]; e0 = e; }
      int e1 = -1; float s1 = -3.4e38f;
      #pragma unroll
      for (int e=0;e<8;e++) if (e != e0 && p[e] > s1){ s1 = p[e]; e1 = e; }
      s_e0[slot] = e0; s_e1[slot] = e1;
      s_w0[slot] = 1.f / (1.f + expf(s1 - s0));
      s_l0[slot] = atomicAdd(&h[e0], 1);     // LDS atomics: cheap local ranks
      s_l1[slot] = atomicAdd(&h[e1], 1);
    }
  }
  __syncthreads();
  if (threadIdx.x < 8)                        // 8 global atomics/block, 64B-padded counters
    basev[threadIdx.x] = atomicAdd(cnt + threadIdx.x*16, h[threadIdx.x]);
  __syncthreads();
  if (threadIdx.x < RTOK){
    const int slot = threadIdx.x;
    const int n = blockIdx.x*RTOK + slot;
    const int e0 = s_e0[slot], e1 = s_e1[slot];
    const float w0 = s_w0[slot];
    tokinfo[n] = make_int4(e0, e1, basev[e0]+s_l0[slot], basev[e1]+s_l1[slot]);
    tw[n] = make_float2(w0, 1.f - w0);
    tok[n] = n;       // shared segment (rows 0..NT): identity
    wgt[n] = 1.0f;
  }
}

// ---------------- segment offsets, rb->expert table, pad init, scatter ----------------
__global__ __launch_bounds__(256) void build_lists_kernel(
    int* __restrict__ meta, int* __restrict__ tok, float* __restrict__ wgt,
    const int4* __restrict__ tokinfo, const float2* __restrict__ tw)
{
  __shared__ int s_off[9];
  const int t = threadIdx.x;
  if (t == 0){
    int off = NT;
    for (int e=0;e<NEXP;e++){ meta[200+e] = off; off += ((meta[e*16]+127)>>7)<<7; }
    meta[208] = off;
    meta[210] = off >> 7;                      // nrb
    for (int rb=0; rb<32; rb++) meta[212+rb] = 8;   // shared segment
    for (int e=0;e<NEXP;e++){
      int b0 = meta[200+e] >> 7, b1 = meta[201+e] >> 7;
      for (int rb=b0; rb<b1; rb++) meta[212+rb] = e;
    }
    for (int e=0;e<9;e++) s_off[e] = meta[200+e];
  }
  __syncthreads();
  const int end = s_off[8];
  for (int i = NT + t; i < end; i += 256) tok[i] = -1;
  __syncthreads();
  for (int n = t; n < NT; n += 256){
    int4 ti = tokinfo[n];
    float2 w = tw[n];
    int a0 = s_off[ti.x] + ti.z; tok[a0] = n; wgt[a0] = w.x;
    int a1 = s_off[ti.y] + ti.w; tok[a1] = n; wgt[a1] = w.y;
  }
}

// ---------------- GEMM1: h = silu(x@Wg) * (x@Wu), gathered rows, bf16 out ----------------
__global__ __launch_bounds__(256,2) void gemm1_kernel(
    const u16* __restrict__ xb, const u16* __restrict__ WgT, const u16* __restrict__ WuT,
    const u16* __restrict__ SgT, const u16* __restrict__ SuT,
    const int* __restrict__ tok, const int* __restrict__ meta, u16* __restrict__ Hbuf)
{
  const int rb = blockIdx.y;
  if (rb >= meta[210]) return;
  const int e = meta[212+rb];
  const u16* __restrict__ Bg = (e < NEXP) ? (WgT + (size_t)e*ID*HD) : SgT;
  const u16* __restrict__ Bu = (e < NEXP) ? (WuT + (size_t)e*ID*HD) : SuT;
  const int n0 = blockIdx.x << 7;
  const int a0 = rb << 7;
  __shared__ u16 smem[24576];                 // 48 KiB: A | G | U tiles (128 x 64 bf16 each)
  u16* sA = smem; u16* sG = smem + 8192; u16* sU = smem + 16384;
  const int tid = threadIdx.x;
  const int wave = tid >> 6, lane = tid & 63;
  const int wr = wave >> 1, wc = wave & 1;
  const int kb = lane & 7;
  int trowA[4];
  #pragma unroll
  for (int r=0;r<4;r++){
    int row = (wave*4+r)*8 + (lane>>3);
    int tt = tok[a0 + row];
    trowA[r] = (tt < 0) ? 0 : tt;             // pad rows read row 0 (discarded later)
  }
  f32x4 accG[4][4], accU[4][4];
  const f32x4 zz = {0.f,0.f,0.f,0.f};
  #pragma unroll
  for (int mi=0;mi<4;mi++)
    #pragma unroll
    for (int ni=0;ni<4;ni++){ accG[mi][ni] = zz; accU[mi][ni] = zz; }

  for (int it=0; it<HD/64; ++it){
    const int k0 = it*64;
    #pragma unroll
    for (int r=0;r<4;r++){
      const int chunk = wave*4 + r;
      const int row = chunk*8 + (lane>>3);
      gld16(xb + (size_t)trowA[r]*HD + k0 + kb*8, sA + chunk*512);
      gld16(Bg + (size_t)(n0+row)*HD + k0 + kb*8, sG + chunk*512);
      gld16(Bu + (size_t)(n0+row)*HD + k0 + kb*8, sU + chunk*512);
    }
    __syncthreads();
    #pragma unroll
    for (int ks=0; ks<2; ++ks){
      const int ko = ks*32 + ((lane>>4)<<3);
      bf16x8 av[4];
      #pragma unroll
      for (int mi=0;mi<4;mi++)
        av[mi] = *(const bf16x8*)(sA + (wr*64+mi*16+(lane&15))*64 + ko);
      #pragma unroll
      for (int ni=0;ni<4;ni++){
        bf16x8 gv = *(const bf16x8*)(sG + (wc*64+ni*16+(lane&15))*64 + ko);
        bf16x8 uv = *(const bf16x8*)(sU + (wc*64+ni*16+(lane&15))*64 + ko);
        #pragma unroll
        for (int mi=0;mi<4;mi++){
          accG[mi][ni] = __builtin_amdgcn_mfma_f32_16x16x32_bf16(av[mi], gv, accG[mi][ni], 0,0,0);
          accU[mi][ni] = __builtin_amdgcn_mfma_f32_16x16x32_bf16(av[mi], uv, accU[mi][ni], 0,0,0);
        }
      }
    }
    __syncthreads();
  }
  // epilogue: silu(g)*u -> bf16 tile in LDS -> coalesced store
  u16* hT = smem;                              // 128x128 bf16 = 32 KiB
  #pragma unroll
  for (int mi=0;mi<4;mi++){
    #pragma unroll
    for (int ni=0;ni<4;ni++){
      const int col = wc*64 + ni*16 + (lane&15);
      #pragma unroll
      for (int j=0;j<4;j++){
        const int row = wr*64 + mi*16 + ((lane>>4)<<2) + j;
        const float g = accG[mi][ni][j], u = accU[mi][ni][j];
        const float h = (g / (1.f + __expf(-g))) * u;
        hT[row*128 + col] = f2bf(h);
      }
    }
  }
  __syncthreads();
  #pragma unroll
  for (int r=0;r<8;r++){
    const int o = r*2048 + tid*8;
    const int row = o >> 7, col = o & 127;
    *(u16x8*)(Hbuf + (size_t)(a0+row)*ID + n0 + col) = *(const u16x8*)(hT + o);
  }
}

// ---------------- GEMM2: y = h @ Wd, weighted atomic scatter-add into out ----------------
__global__ __launch_bounds__(256,2) void gemm2_kernel(
    const u16* __restrict__ Hbuf, const u16* __restrict__ WdT, const u16* __restrict__ SdT,
    const int* __restrict__ tok, const float* __restrict__ wgt,
    const int* __restrict__ meta, float* __restrict__ out)
{
  const int rb = blockIdx.y;
  if (rb >= meta[210]) return;
  const int e = meta[212+rb];
  const u16* __restrict__ Bd = (e < NEXP) ? (WdT + (size_t)e*HD*ID) : SdT;
  const int n0 = blockIdx.x << 7;
  const int a0 = rb << 7;
  __shared__ u16 smem[16384];                  // 32 KiB: A | B tiles
  u16* sA = smem; u16* sB = smem + 8192;
  const int tid = threadIdx.x;
  const int wave = tid >> 6, lane = tid & 63;
  const int wr = wave >> 1, wc = wave & 1;
  const int kb = lane & 7;
  f32x4 acc[4][4];
  const f32x4 zz = {0.f,0.f,0.f,0.f};
  #pragma unroll
  for (int mi=0;mi<4;mi++)
    #pragma unroll
    for (int ni=0;ni<4;ni++) acc[mi][ni] = zz;

  for (int it=0; it<ID/64; ++it){
    const int k0 = it*64;
    #pragma unroll
    for (int r=0;r<4;r++){
      const int chunk = wave*4 + r;
      const int row = chunk*8 + (lane>>3);
      gld16(Hbuf + (size_t)(a0+row)*ID + k0 + kb*8, sA + chunk*512);
      gld16(Bd   + (size_t)(n0+row)*ID + k0 + kb*8, sB + chunk*512);
    }
    __syncthreads();
    #pragma unroll
    for (int ks=0; ks<2; ++ks){
      const int ko = ks*32 + ((lane>>4)<<3);
      bf16x8 av[4];
      #pragma unroll
      for (int mi=0;mi<4;mi++)
        av[mi] = *(const bf16x8*)(sA + (wr*64+mi*16+(lane&15))*64 + ko);
      #pragma unroll
      for (int ni=0;ni<4;ni++){
        bf16x8 bv = *(const bf16x8*)(sB + (wc*64+ni*16+(lane&15))*64 + ko);
        #pragma unroll
        for (int mi=0;mi<4;mi++)
          acc[mi][ni] = __builtin_amdgcn_mfma_f32_16x16x32_bf16(av[mi], bv, acc[mi][ni], 0,0,0);
      }
    }
    __syncthreads();
  }
  #pragma unroll
  for (int mi=0;mi<4;mi++){
    #pragma unroll
    for (int j=0;j<4;j++){
      const int row = wr*64 + mi*16 + ((lane>>4)<<2) + j;
      const int a = a0 + row;
      const int t = tok[a];
      if (t < 0) continue;
      const float w = wgt[a];
      float* orow = out + (size_t)t*HD + n0 + wc*64 + (lane&15);
      #pragma unroll
      for (int ni=0;ni<4;ni++)
        atomicAdd(orow + ni*16, w * acc[mi][ni][j]);
    }
  }
}

extern "C" void kernel_launch(void* const* d_in, const int* in_sizes, int n_in,
                              void* d_out, int out_size, void* d_ws, size_t ws_size,
                              hipStream_t stream)
{
  (void)in_sizes; (void)n_in;
  if (ws_size < WS_NEED) return;
  const float* x  = (const float*)d_in[0];
  const float* rw = (const float*)d_in[1];
  const float* Wg = (const float*)d_in[2];
  const float* Wu = (const float*)d_in[3];
  const float* Wd = (const float*)d_in[4];
  const float* Sg = (const float*)d_in[5];
  const float* Su = (const float*)d_in[6];
  const float* Sd = (const float*)d_in[7];
  float* out = (float*)d_out;
  char* ws = (char*)d_ws;
  u16*   xb   = (u16*)  (ws + OFF_XB);
  u16*   WgT  = (u16*)  (ws + OFF_WGT);
  u16*   WuT  = (u16*)  (ws + OFF_WUT);
  u16*   WdT  = (u16*)  (ws + OFF_WDT);
  u16*   SgT  = (u16*)  (ws + OFF_SGT);
  u16*   SuT  = (u16*)  (ws + OFF_SUT);
  u16*   SdT  = (u16*)  (ws + OFF_SDT);
  u16*   Hbuf = (u16*)  (ws + OFF_HBUF);
  int*   tok  = (int*)  (ws + OFF_TOK);
  float* wgt  = (float*)(ws + OFF_WGTW);
  int4*  ti   = (int4*) (ws + OFF_TI);
  float2* tw  = (float2*)(ws + OFF_TW);
  int*   meta = (int*)  (ws + OFF_META);

  hipMemsetAsync(out, 0, (size_t)out_size * sizeof(float), stream);
  hipMemsetAsync(meta, 0, 512, stream);   // padded cnt[8] (stride-16 ints)

  transpose_convert_kernel<<<13824, 256, 0, stream>>>(Wg,Wu,Wd,Sg,Su,Sd, WgT,WuT,WdT,SgT,SuT,SdT);
  router_kernel<<<NT/RTOK, 256, 0, stream>>>(x, rw, xb, tok, wgt, ti, tw, meta);
  build_lists_kernel<<<1, 256, 0, stream>>>(meta, tok, wgt, ti, tw);
  gemm1_kernel<<<dim3(ID/128, MAXRB), 256, 0, stream>>>(xb, WgT, WuT, SgT, SuT, tok, meta, Hbuf);
  gemm2_kernel<<<dim3(HD/128, MAXRB), 256, 0, stream>>>(Hbuf, WdT, SdT, tok, wgt, meta, out);
}

// Round 8
// 231.386 us; speedup vs baseline: 1.3684x; 1.0542x over previous
//
#include <hip/hip_runtime.h>

typedef unsigned short u16;
typedef u16 u16x8 __attribute__((ext_vector_type(8)));
typedef __bf16 bf16x8 __attribute__((ext_vector_type(8)));
typedef float f32x4 __attribute__((ext_vector_type(4)));

constexpr int NT   = 4096;   // tokens = B*T
constexpr int HD   = 512;    // hidden
constexpr int ID   = 1024;   // inter
constexpr int NEXP = 8;
constexpr int ROWCAP = 13312;   // 4096 shared + 9216 padded routed (104*128)
constexpr int MAXRB  = 104;

// ---- workspace layout (bytes) ----
constexpr size_t OFF_XB   = 0;
constexpr size_t OFF_WGT  = OFF_XB   + (size_t)NT*HD*2;
constexpr size_t OFF_WUT  = OFF_WGT  + (size_t)NEXP*ID*HD*2;
constexpr size_t OFF_WDT  = OFF_WUT  + (size_t)NEXP*ID*HD*2;
constexpr size_t OFF_SGT  = OFF_WDT  + (size_t)NEXP*HD*ID*2;
constexpr size_t OFF_SUT  = OFF_SGT  + (size_t)ID*HD*2;
constexpr size_t OFF_SDT  = OFF_SUT  + (size_t)ID*HD*2;
constexpr size_t OFF_HBUF = OFF_SDT  + (size_t)HD*ID*2;
constexpr size_t OFF_TOK  = OFF_HBUF + (size_t)ROWCAP*ID*2;
constexpr size_t OFF_WGTW = OFF_TOK  + (size_t)ROWCAP*4;
constexpr size_t OFF_TI   = OFF_WGTW + (size_t)ROWCAP*4;
constexpr size_t OFF_TW   = OFF_TI   + (size_t)NT*16;
constexpr size_t OFF_META = OFF_TW   + (size_t)NT*8;
constexpr size_t WS_NEED  = OFF_META + 2048;
// meta int layout:
//   [e*16]           e=0..7   : padded expert counters (64B apart -> no shared cache line)
//   [200..208]                : segoff[0..8] (segoff[8] = total padded rows at [208])
//   [210]                     : nrb
//   [212..316)                : rbe (row-block -> expert table)

__device__ __forceinline__ u16 f2bf(float f){
  unsigned int u = __float_as_uint(f);
  u += 0x7fffu + ((u >> 16) & 1u);
  return (u16)(u >> 16);
}

#define AS1C(p) ((const __attribute__((address_space(1))) void*)(p))
#define AS3(p)  ((__attribute__((address_space(3))) void*)(p))
__device__ __forceinline__ void gld16(const void* g, void* l){
  __builtin_amdgcn_global_load_lds(AS1C(g), AS3(l), 16, 0, 0);
}

// ---------------- weight transpose+convert: fp32 [R][C] -> bf16 [C][R] ----------------
__global__ __launch_bounds__(256) void transpose_convert_kernel(
    const float* __restrict__ Wg, const float* __restrict__ Wu, const float* __restrict__ Wd,
    const float* __restrict__ Sg, const float* __restrict__ Su, const float* __restrict__ Sd,
    u16* __restrict__ WgT, u16* __restrict__ WuT, u16* __restrict__ WdT,
    u16* __restrict__ SgT, u16* __restrict__ SuT, u16* __restrict__ SdT)
{
  int b = blockIdx.x;
  const float* src; u16* dst; int R, C, t;
  if (b < 4096)      { int e=b>>9; t=b&511; src=Wg+(size_t)e*HD*ID; dst=WgT+(size_t)e*ID*HD; R=HD; C=ID; }
  else if (b < 8192) { b-=4096; int e=b>>9; t=b&511; src=Wu+(size_t)e*HD*ID; dst=WuT+(size_t)e*ID*HD; R=HD; C=ID; }
  else if (b < 12288){ b-=8192; int e=b>>9; t=b&511; src=Wd+(size_t)e*ID*HD; dst=WdT+(size_t)e*HD*ID; R=ID; C=HD; }
  else if (b < 12800){ t=b-12288; src=Sg; dst=SgT; R=HD; C=ID; }
  else if (b < 13312){ t=b-12800; src=Su; dst=SuT; R=HD; C=ID; }
  else               { t=b-13312; src=Sd; dst=SdT; R=ID; C=HD; }
  const int tc = C >> 5;
  const int r0 = (t / tc) << 5, c0 = (t % tc) << 5;
  __shared__ float tile[32][33];
  const int tx = threadIdx.x & 31, ty = threadIdx.x >> 5;
  #pragma unroll
  for (int j=0;j<4;j++) tile[ty+j*8][tx] = src[(size_t)(r0+ty+j*8)*C + c0+tx];
  __syncthreads();
  #pragma unroll
  for (int j=0;j<4;j++) dst[(size_t)(c0+ty+j*8)*R + r0+tx] = f2bf(tile[tx][ty+j*8]);
}

// ---------------- router: per-block aggregated counting ----------------
constexpr int RTOK = 32;   // tokens per block (8 per wave)
__global__ __launch_bounds__(256) void router_kernel(
    const float* __restrict__ x, const float* __restrict__ rw,
    u16* __restrict__ xb, int* __restrict__ tok, float* __restrict__ wgt,
    int4* __restrict__ tokinfo, float2* __restrict__ tw, int* __restrict__ cnt)
{
  const int wave = threadIdx.x >> 6, lane = threadIdx.x & 63;
  __shared__ int h[8];
  __shared__ int basev[8];
  __shared__ int s_e0[RTOK], s_e1[RTOK], s_l0[RTOK], s_l1[RTOK];
  __shared__ float s_w0[RTOK];
  if (threadIdx.x < 8) h[threadIdx.x] = 0;
  __syncthreads();

  #pragma unroll
  for (int t=0; t<RTOK/4; ++t){
    const int slot = wave*(RTOK/4) + t;
    const int n = blockIdx.x*RTOK + slot;
    const float4 xv0 = *(const float4*)(x + (size_t)n*HD + lane*8);
    const float4 xv1 = *(const float4*)(x + (size_t)n*HD + lane*8 + 4);
    u16x8 xs;
    xs[0]=f2bf(xv0.x); xs[1]=f2bf(xv0.y); xs[2]=f2bf(xv0.z); xs[3]=f2bf(xv0.w);
    xs[4]=f2bf(xv1.x); xs[5]=f2bf(xv1.y); xs[6]=f2bf(xv1.z); xs[7]=f2bf(xv1.w);
    *(u16x8*)(xb + (size_t)n*HD + lane*8) = xs;
    const float xa[8] = {xv0.x,xv0.y,xv0.z,xv0.w,xv1.x,xv1.y,xv1.z,xv1.w};
    float p[8] = {0,0,0,0,0,0,0,0};
    const float4* rp = (const float4*)(rw + (size_t)lane*8*NEXP);
    #pragma unroll
    for (int j=0;j<8;j++){
      float4 r0 = rp[j*2], r1 = rp[j*2+1];
      p[0]+=xa[j]*r0.x; p[1]+=xa[j]*r0.y; p[2]+=xa[j]*r0.z; p[3]+=xa[j]*r0.w;
      p[4]+=xa[j]*r1.x; p[5]+=xa[j]*r1.y; p[6]+=xa[j]*r1.z; p[7]+=xa[j]*r1.w;
    }
    #pragma unroll
    for (int m=1;m<64;m<<=1){
      #pragma unroll
      for (int e=0;e<8;e++) p[e] += __shfl_xor(p[e], m, 64);
    }
    if (lane == 0){
      int e0 = 0; float s0 = p[0];
      #pragma unroll
      for (int e=1;e<8;e++) if (p[e] > s0){ s0 = p[e]; e0 = e; }
      int e1 = -1; float s1 = -3.4e38f;
      #pragma unroll
      for (int e=0;e<8;e++) if (e != e0 && p[e] > s1){ s1 = p[e]; e1 = e; }
      s_e0[slot] = e0; s_e1[slot] = e1;
      s_w0[slot] = 1.f / (1.f + expf(s1 - s0));
      s_l0[slot] = atomicAdd(&h[e0], 1);     // LDS atomics: cheap local ranks
      s_l1[slot] = atomicAdd(&h[e1], 1);
    }
  }
  __syncthreads();
  if (threadIdx.x < 8)                        // 8 global atomics/block, 64B-padded counters
    basev[threadIdx.x] = atomicAdd(cnt + threadIdx.x*16, h[threadIdx.x]);
  __syncthreads();
  if (threadIdx.x < RTOK){
    const int slot = threadIdx.x;
    const int n = blockIdx.x*RTOK + slot;
    const int e0 = s_e0[slot], e1 = s_e1[slot];
    const float w0 = s_w0[slot];
    tokinfo[n] = make_int4(e0, e1, basev[e0]+s_l0[slot], basev[e1]+s_l1[slot]);
    tw[n] = make_float2(w0, 1.f - w0);
    tok[n] = n;       // shared segment (rows 0..NT): identity
    wgt[n] = 1.0f;
  }
}

// ---------------- segment offsets, rb->expert table, pad init, scatter ----------------
__global__ __launch_bounds__(256) void build_lists_kernel(
    int* __restrict__ meta, int* __restrict__ tok, float* __restrict__ wgt,
    const int4* __restrict__ tokinfo, const float2* __restrict__ tw)
{
  __shared__ int s_off[9];
  const int t = threadIdx.x;
  if (t == 0){
    int off = NT;
    for (int e=0;e<NEXP;e++){ meta[200+e] = off; off += ((meta[e*16]+127)>>7)<<7; }
    meta[208] = off;
    meta[210] = off >> 7;                      // nrb
    for (int rb=0; rb<32; rb++) meta[212+rb] = 8;   // shared segment
    for (int e=0;e<NEXP;e++){
      int b0 = meta[200+e] >> 7, b1 = meta[201+e] >> 7;
      for (int rb=b0; rb<b1; rb++) meta[212+rb] = e;
    }
    for (int e=0;e<9;e++) s_off[e] = meta[200+e];
  }
  __syncthreads();
  const int end = s_off[8];
  for (int i = NT + t; i < end; i += 256) tok[i] = -1;
  __syncthreads();
  for (int n = t; n < NT; n += 256){
    int4 ti = tokinfo[n];
    float2 w = tw[n];
    int a0 = s_off[ti.x] + ti.z; tok[a0] = n; wgt[a0] = w.x;
    int a1 = s_off[ti.y] + ti.w; tok[a1] = n; wgt[a1] = w.y;
  }
}

// ---------------- GEMM1: h = silu(x@Wg) * (x@Wu), gathered rows, bf16 out ----------------
// T2 LDS swizzle: global source column-block permuted (kb = (lane&7)^(lane>>3)) so the
// linear global_load_lds dest yields LDS[row][col ^ ((row&7)<<3)]; fragment reads XOR back.
__global__ __launch_bounds__(256,2) void gemm1_kernel(
    const u16* __restrict__ xb, const u16* __restrict__ WgT, const u16* __restrict__ WuT,
    const u16* __restrict__ SgT, const u16* __restrict__ SuT,
    const int* __restrict__ tok, const int* __restrict__ meta, u16* __restrict__ Hbuf)
{
  const int rb = blockIdx.y;
  if (rb >= meta[210]) return;
  const int e = meta[212+rb];
  const u16* __restrict__ Bg = (e < NEXP) ? (WgT + (size_t)e*ID*HD) : SgT;
  const u16* __restrict__ Bu = (e < NEXP) ? (WuT + (size_t)e*ID*HD) : SuT;
  const int n0 = blockIdx.x << 7;
  const int a0 = rb << 7;
  __shared__ u16 smem[24576];                 // 48 KiB: A | G | U tiles (128 x 64 bf16 each)
  u16* sA = smem; u16* sG = smem + 8192; u16* sU = smem + 16384;
  const int tid = threadIdx.x;
  const int wave = tid >> 6, lane = tid & 63;
  const int wr = wave >> 1, wc = wave & 1;
  const int kb = (lane & 7) ^ (lane >> 3);     // swizzled source k-block
  const int sw = (lane & 7) << 3;              // read-side XOR (row&7 == lane&7)
  int trowA[4];
  #pragma unroll
  for (int r=0;r<4;r++){
    int row = (wave*4+r)*8 + (lane>>3);
    int tt = tok[a0 + row];
    trowA[r] = (tt < 0) ? 0 : tt;             // pad rows read row 0 (discarded later)
  }
  f32x4 accG[4][4], accU[4][4];
  const f32x4 zz = {0.f,0.f,0.f,0.f};
  #pragma unroll
  for (int mi=0;mi<4;mi++)
    #pragma unroll
    for (int ni=0;ni<4;ni++){ accG[mi][ni] = zz; accU[mi][ni] = zz; }

  for (int it=0; it<HD/64; ++it){
    const int k0 = it*64;
    #pragma unroll
    for (int r=0;r<4;r++){
      const int chunk = wave*4 + r;
      const int row = chunk*8 + (lane>>3);
      gld16(xb + (size_t)trowA[r]*HD + k0 + kb*8, sA + chunk*512);
      gld16(Bg + (size_t)(n0+row)*HD + k0 + kb*8, sG + chunk*512);
      gld16(Bu + (size_t)(n0+row)*HD + k0 + kb*8, sU + chunk*512);
    }
    __syncthreads();
    #pragma unroll
    for (int ks=0; ks<2; ++ks){
      const int ko = ks*32 + ((lane>>4)<<3);
      const int kx = ko ^ sw;
      bf16x8 av[4];
      #pragma unroll
      for (int mi=0;mi<4;mi++)
        av[mi] = *(const bf16x8*)(sA + (wr*64+mi*16+(lane&15))*64 + kx);
      #pragma unroll
      for (int ni=0;ni<4;ni++){
        bf16x8 gv = *(const bf16x8*)(sG + (wc*64+ni*16+(lane&15))*64 + kx);
        bf16x8 uv = *(const bf16x8*)(sU + (wc*64+ni*16+(lane&15))*64 + kx);
        #pragma unroll
        for (int mi=0;mi<4;mi++){
          accG[mi][ni] = __builtin_amdgcn_mfma_f32_16x16x32_bf16(av[mi], gv, accG[mi][ni], 0,0,0);
          accU[mi][ni] = __builtin_amdgcn_mfma_f32_16x16x32_bf16(av[mi], uv, accU[mi][ni], 0,0,0);
        }
      }
    }
    __syncthreads();
  }
  // epilogue: silu(g)*u -> bf16 tile in LDS -> coalesced store
  u16* hT = smem;                              // 128x128 bf16 = 32 KiB
  #pragma unroll
  for (int mi=0;mi<4;mi++){
    #pragma unroll
    for (int ni=0;ni<4;ni++){
      const int col = wc*64 + ni*16 + (lane&15);
      #pragma unroll
      for (int j=0;j<4;j++){
        const int row = wr*64 + mi*16 + ((lane>>4)<<2) + j;
        const float g = accG[mi][ni][j], u = accU[mi][ni][j];
        const float h = (g / (1.f + __expf(-g))) * u;
        hT[row*128 + col] = f2bf(h);
      }
    }
  }
  __syncthreads();
  #pragma unroll
  for (int r=0;r<8;r++){
    const int o = r*2048 + tid*8;
    const int row = o >> 7, col = o & 127;
    *(u16x8*)(Hbuf + (size_t)(a0+row)*ID + n0 + col) = *(const u16x8*)(hT + o);
  }
}

// ---------------- GEMM2: y = h @ Wd, weighted atomic scatter-add into out ----------------
__global__ __launch_bounds__(256,2) void gemm2_kernel(
    const u16* __restrict__ Hbuf, const u16* __restrict__ WdT, const u16* __restrict__ SdT,
    const int* __restrict__ tok, const float* __restrict__ wgt,
    const int* __restrict__ meta, float* __restrict__ out)
{
  const int rb = blockIdx.y;
  if (rb >= meta[210]) return;
  const int e = meta[212+rb];
  const u16* __restrict__ Bd = (e < NEXP) ? (WdT + (size_t)e*HD*ID) : SdT;
  const int n0 = blockIdx.x << 7;
  const int a0 = rb << 7;
  __shared__ u16 smem[16384];                  // 32 KiB: A | B tiles
  u16* sA = smem; u16* sB = smem + 8192;
  const int tid = threadIdx.x;
  const int wave = tid >> 6, lane = tid & 63;
  const int wr = wave >> 1, wc = wave & 1;
  const int kb = (lane & 7) ^ (lane >> 3);     // swizzled source k-block
  const int sw = (lane & 7) << 3;              // read-side XOR
  f32x4 acc[4][4];
  const f32x4 zz = {0.f,0.f,0.f,0.f};
  #pragma unroll
  for (int mi=0;mi<4;mi++)
    #pragma unroll
    for (int ni=0;ni<4;ni++) acc[mi][ni] = zz;

  for (int it=0; it<ID/64; ++it){
    const int k0 = it*64;
    #pragma unroll
    for (int r=0;r<4;r++){
      const int chunk = wave*4 + r;
      const int row = chunk*8 + (lane>>3);
      gld16(Hbuf + (size_t)(a0+row)*ID + k0 + kb*8, sA + chunk*512);
      gld16(Bd   + (size_t)(n0+row)*ID + k0 + kb*8, sB + chunk*512);
    }
    __syncthreads();
    #pragma unroll
    for (int ks=0; ks<2; ++ks){
      const int ko = ks*32 + ((lane>>4)<<3);
      const int kx = ko ^ sw;
      bf16x8 av[4];
      #pragma unroll
      for (int mi=0;mi<4;mi++)
        av[mi] = *(const bf16x8*)(sA + (wr*64+mi*16+(lane&15))*64 + kx);
      #pragma unroll
      for (int ni=0;ni<4;ni++){
        bf16x8 bv = *(const bf16x8*)(sB + (wc*64+ni*16+(lane&15))*64 + kx);
        #pragma unroll
        for (int mi=0;mi<4;mi++)
          acc[mi][ni] = __builtin_amdgcn_mfma_f32_16x16x32_bf16(av[mi], bv, acc[mi][ni], 0,0,0);
      }
    }
    __syncthreads();
  }
  #pragma unroll
  for (int mi=0;mi<4;mi++){
    #pragma unroll
    for (int j=0;j<4;j++){
      const int row = wr*64 + mi*16 + ((lane>>4)<<2) + j;
      const int a = a0 + row;
      const int t = tok[a];
      if (t < 0) continue;
      const float w = wgt[a];
      float* orow = out + (size_t)t*HD + n0 + wc*64 + (lane&15);
      #pragma unroll
      for (int ni=0;ni<4;ni++)
        atomicAdd(orow + ni*16, w * acc[mi][ni][j]);
    }
  }
}

extern "C" void kernel_launch(void* const* d_in, const int* in_sizes, int n_in,
                              void* d_out, int out_size, void* d_ws, size_t ws_size,
                              hipStream_t stream)
{
  (void)in_sizes; (void)n_in;
  if (ws_size < WS_NEED) return;
  const float* x  = (const float*)d_in[0];
  const float* rw = (const float*)d_in[1];
  const float* Wg = (const float*)d_in[2];
  const float* Wu = (const float*)d_in[3];
  const float* Wd = (const float*)d_in[4];
  const float* Sg = (const float*)d_in[5];
  const float* Su = (const float*)d_in[6];
  const float* Sd = (const float*)d_in[7];
  float* out = (float*)d_out;
  char* ws = (char*)d_ws;
  u16*   xb   = (u16*)  (ws + OFF_XB);
  u16*   WgT  = (u16*)  (ws + OFF_WGT);
  u16*   WuT  = (u16*)  (ws + OFF_WUT);
  u16*   WdT  = (u16*)  (ws + OFF_WDT);
  u16*   SgT  = (u16*)  (ws + OFF_SGT);
  u16*   SuT  = (u16*)  (ws + OFF_SUT);
  u16*   SdT  = (u16*)  (ws + OFF_SDT);
  u16*   Hbuf = (u16*)  (ws + OFF_HBUF);
  int*   tok  = (int*)  (ws + OFF_TOK);
  float* wgt  = (float*)(ws + OFF_WGTW);
  int4*  ti   = (int4*) (ws + OFF_TI);
  float2* tw  = (float2*)(ws + OFF_TW);
  int*   meta = (int*)  (ws + OFF_META);

  hipMemsetAsync(out, 0, (size_t)out_size * sizeof(float), stream);
  hipMemsetAsync(meta, 0, 512, stream);   // padded cnt[8] (stride-16 ints)

  transpose_convert_kernel<<<13824, 256, 0, stream>>>(Wg,Wu,Wd,Sg,Su,Sd, WgT,WuT,WdT,SgT,SuT,SdT);
  router_kernel<<<NT/RTOK, 256, 0, stream>>>(x, rw, xb, tok, wgt, ti, tw, meta);
  build_lists_kernel<<<1, 256, 0, stream>>>(meta, tok, wgt, ti, tw);
  gemm1_kernel<<<dim3(ID/128, MAXRB), 256, 0, stream>>>(xb, WgT, WuT, SgT, SuT, tok, meta, Hbuf);
  gemm2_kernel<<<dim3(HD/128, MAXRB), 256, 0, stream>>>(Hbuf, WdT, SdT, tok, wgt, meta, out);
}

// Round 10
// 220.487 us; speedup vs baseline: 1.4361x; 1.0494x over previous
//
#include <hip/hip_runtime.h>

typedef unsigned short u16;
typedef u16 u16x8 __attribute__((ext_vector_type(8)));
typedef __bf16 bf16x8 __attribute__((ext_vector_type(8)));
typedef float f32x4 __attribute__((ext_vector_type(4)));

constexpr int NT   = 4096;   // tokens = B*T
constexpr int HD   = 512;    // hidden
constexpr int ID   = 1024;   // inter
constexpr int NEXP = 8;
constexpr int ROWCAP = 13312;   // 4096 shared + 9216 padded routed (104*128)
constexpr int MAXRB  = 104;

// ---- workspace layout (bytes) ----
constexpr size_t OFF_XB   = 0;
constexpr size_t OFF_WGT  = OFF_XB   + (size_t)NT*HD*2;
constexpr size_t OFF_WUT  = OFF_WGT  + (size_t)NEXP*ID*HD*2;
constexpr size_t OFF_WDT  = OFF_WUT  + (size_t)NEXP*ID*HD*2;
constexpr size_t OFF_SGT  = OFF_WDT  + (size_t)NEXP*HD*ID*2;
constexpr size_t OFF_SUT  = OFF_SGT  + (size_t)ID*HD*2;
constexpr size_t OFF_SDT  = OFF_SUT  + (size_t)ID*HD*2;
constexpr size_t OFF_HBUF = OFF_SDT  + (size_t)HD*ID*2;
constexpr size_t OFF_TOK  = OFF_HBUF + (size_t)ROWCAP*ID*2;
constexpr size_t OFF_WGTW = OFF_TOK  + (size_t)ROWCAP*4;
constexpr size_t OFF_TI   = OFF_WGTW + (size_t)ROWCAP*4;
constexpr size_t OFF_TW   = OFF_TI   + (size_t)NT*16;
constexpr size_t OFF_META = OFF_TW   + (size_t)NT*8;
constexpr size_t WS_NEED  = OFF_META + 2048;
// Ybuf (bf16, ROWCAP x HD = 13.6 MB) aliases WgT+WuT (16.8 MB combined).
// RACE AUDIT (round-9 tripwire fix): the f32 Ybuf (27.3 MB) overflowed into
// WdT/SgT/SuT which gemm2 READS while writing Ybuf -> nondeterminism. bf16
// Ybuf fits strictly inside WgT+WuT, which are dead after gemm1 (stream-
// ordered before gemm2). gemm2 reads only Hbuf/WdT/SdT/tok/meta: no overlap.
constexpr size_t OFF_YB   = OFF_WGT;
static_assert((size_t)ROWCAP*HD*2 <= (size_t)2*NEXP*ID*HD*2, "Ybuf must fit in WgT+WuT");
// meta int layout:
//   [e*16]           e=0..7   : padded expert counters (64B apart -> no shared cache line)
//   [200..208]                : segoff[0..8] (segoff[8] = total padded rows at [208])
//   [210]                     : nrb
//   [212..316)                : rbe (row-block -> expert table)

__device__ __forceinline__ u16 f2bf(float f){
  unsigned int u = __float_as_uint(f);
  u += 0x7fffu + ((u >> 16) & 1u);
  return (u16)(u >> 16);
}
__device__ __forceinline__ float bf2f(u16 v){
  return __uint_as_float(((unsigned int)v) << 16);
}

#define AS1C(p) ((const __attribute__((address_space(1))) void*)(p))
#define AS3(p)  ((__attribute__((address_space(3))) void*)(p))
__device__ __forceinline__ void gld16(const void* g, void* l){
  __builtin_amdgcn_global_load_lds(AS1C(g), AS3(l), 16, 0, 0);
}

// ---------------- weight transpose+convert: fp32 [R][C] -> bf16 [C][R] ----------------
__global__ __launch_bounds__(256) void transpose_convert_kernel(
    const float* __restrict__ Wg, const float* __restrict__ Wu, const float* __restrict__ Wd,
    const float* __restrict__ Sg, const float* __restrict__ Su, const float* __restrict__ Sd,
    u16* __restrict__ WgT, u16* __restrict__ WuT, u16* __restrict__ WdT,
    u16* __restrict__ SgT, u16* __restrict__ SuT, u16* __restrict__ SdT)
{
  int b = blockIdx.x;
  const float* src; u16* dst; int R, C, t;
  if (b < 4096)      { int e=b>>9; t=b&511; src=Wg+(size_t)e*HD*ID; dst=WgT+(size_t)e*ID*HD; R=HD; C=ID; }
  else if (b < 8192) { b-=4096; int e=b>>9; t=b&511; src=Wu+(size_t)e*HD*ID; dst=WuT+(size_t)e*ID*HD; R=HD; C=ID; }
  else if (b < 12288){ b-=8192; int e=b>>9; t=b&511; src=Wd+(size_t)e*ID*HD; dst=WdT+(size_t)e*HD*ID; R=ID; C=HD; }
  else if (b < 12800){ t=b-12288; src=Sg; dst=SgT; R=HD; C=ID; }
  else if (b < 13312){ t=b-12800; src=Su; dst=SuT; R=HD; C=ID; }
  else               { t=b-13312; src=Sd; dst=SdT; R=ID; C=HD; }
  const int tc = C >> 5;
  const int r0 = (t / tc) << 5, c0 = (t % tc) << 5;
  __shared__ float tile[32][33];
  const int tx = threadIdx.x & 31, ty = threadIdx.x >> 5;
  #pragma unroll
  for (int j=0;j<4;j++) tile[ty+j*8][tx] = src[(size_t)(r0+ty+j*8)*C + c0+tx];
  __syncthreads();
  #pragma unroll
  for (int j=0;j<4;j++) dst[(size_t)(c0+ty+j*8)*R + r0+tx] = f2bf(tile[tx][ty+j*8]);
}

// ---------------- router: per-block aggregated counting ----------------
constexpr int RTOK = 32;   // tokens per block (8 per wave)
__global__ __launch_bounds__(256) void router_kernel(
    const float* __restrict__ x, const float* __restrict__ rw,
    u16* __restrict__ xb, int* __restrict__ tok, float* __restrict__ wgt,
    int4* __restrict__ tokinfo, float2* __restrict__ tw, int* __restrict__ cnt)
{
  const int wave = threadIdx.x >> 6, lane = threadIdx.x & 63;
  __shared__ int h[8];
  __shared__ int basev[8];
  __shared__ int s_e0[RTOK], s_e1[RTOK], s_l0[RTOK], s_l1[RTOK];
  __shared__ float s_w0[RTOK];
  if (threadIdx.x < 8) h[threadIdx.x] = 0;
  __syncthreads();

  #pragma unroll
  for (int t=0; t<RTOK/4; ++t){
    const int slot = wave*(RTOK/4) + t;
    const int n = blockIdx.x*RTOK + slot;
    const float4 xv0 = *(const float4*)(x + (size_t)n*HD + lane*8);
    const float4 xv1 = *(const float4*)(x + (size_t)n*HD + lane*8 + 4);
    u16x8 xs;
    xs[0]=f2bf(xv0.x); xs[1]=f2bf(xv0.y); xs[2]=f2bf(xv0.z); xs[3]=f2bf(xv0.w);
    xs[4]=f2bf(xv1.x); xs[5]=f2bf(xv1.y); xs[6]=f2bf(xv1.z); xs[7]=f2bf(xv1.w);
    *(u16x8*)(xb + (size_t)n*HD + lane*8) = xs;
    const float xa[8] = {xv0.x,xv0.y,xv0.z,xv0.w,xv1.x,xv1.y,xv1.z,xv1.w};
    float p[8] = {0,0,0,0,0,0,0,0};
    const float4* rp = (const float4*)(rw + (size_t)lane*8*NEXP);
    #pragma unroll
    for (int j=0;j<8;j++){
      float4 r0 = rp[j*2], r1 = rp[j*2+1];
      p[0]+=xa[j]*r0.x; p[1]+=xa[j]*r0.y; p[2]+=xa[j]*r0.z; p[3]+=xa[j]*r0.w;
      p[4]+=xa[j]*r1.x; p[5]+=xa[j]*r1.y; p[6]+=xa[j]*r1.z; p[7]+=xa[j]*r1.w;
    }
    #pragma unroll
    for (int m=1;m<64;m<<=1){
      #pragma unroll
      for (int e=0;e<8;e++) p[e] += __shfl_xor(p[e], m, 64);
    }
    if (lane == 0){
      int e0 = 0; float s0 = p[0];
      #pragma unroll
      for (int e=1;e<8;e++) if (p[e] > s0){ s0 = p[e]; e0 = e; }
      int e1 = -1; float s1 = -3.4e38f;
      #pragma unroll
      for (int e=0;e<8;e++) if (e != e0 && p[e] > s1){ s1 = p[e]; e1 = e; }
      s_e0[slot] = e0; s_e1[slot] = e1;
      s_w0[slot] = 1.f / (1.f + expf(s1 - s0));
      s_l0[slot] = atomicAdd(&h[e0], 1);     // LDS atomics: cheap local ranks
      s_l1[slot] = atomicAdd(&h[e1], 1);
    }
  }
  __syncthreads();
  if (threadIdx.x < 8)                        // 8 global atomics/block, 64B-padded counters
    basev[threadIdx.x] = atomicAdd(cnt + threadIdx.x*16, h[threadIdx.x]);
  __syncthreads();
  if (threadIdx.x < RTOK){
    const int slot = threadIdx.x;
    const int n = blockIdx.x*RTOK + slot;
    const int e0 = s_e0[slot], e1 = s_e1[slot];
    const float w0 = s_w0[slot];
    tokinfo[n] = make_int4(e0, e1, basev[e0]+s_l0[slot], basev[e1]+s_l1[slot]);
    tw[n] = make_float2(w0, 1.f - w0);
    tok[n] = n;       // shared segment (rows 0..NT): identity
    wgt[n] = 1.0f;
  }
}

// ---------------- segment offsets, rb->expert table, pad init, scatter ----------------
__global__ __launch_bounds__(256) void build_lists_kernel(
    int* __restrict__ meta, int* __restrict__ tok, float* __restrict__ wgt,
    const int4* __restrict__ tokinfo, const float2* __restrict__ tw)
{
  __shared__ int s_off[9];
  const int t = threadIdx.x;
  if (t == 0){
    int off = NT;
    for (int e=0;e<NEXP;e++){ meta[200+e] = off; off += ((meta[e*16]+127)>>7)<<7; }
    meta[208] = off;
    meta[210] = off >> 7;                      // nrb
    for (int rb=0; rb<32; rb++) meta[212+rb] = 8;   // shared segment
    for (int e=0;e<NEXP;e++){
      int b0 = meta[200+e] >> 7, b1 = meta[201+e] >> 7;
      for (int rb=b0; rb<b1; rb++) meta[212+rb] = e;
    }
    for (int e=0;e<9;e++) s_off[e] = meta[200+e];
  }
  __syncthreads();
  const int end = s_off[8];
  for (int i = NT + t; i < end; i += 256) tok[i] = -1;
  __syncthreads();
  for (int n = t; n < NT; n += 256){
    int4 ti = tokinfo[n];
    float2 w = tw[n];
    int a0 = s_off[ti.x] + ti.z; tok[a0] = n; wgt[a0] = w.x;
    int a1 = s_off[ti.y] + ti.w; tok[a1] = n; wgt[a1] = w.y;
  }
}

// ---------------- GEMM1: h = silu(x@Wg) * (x@Wu), gathered rows, bf16 out ----------------
// T2 LDS swizzle: global source column-block permuted (kb = (lane&7)^(lane>>3)) so the
// linear global_load_lds dest yields LDS[row][col ^ ((row&7)<<3)]; fragment reads XOR back.
__global__ __launch_bounds__(256,2) void gemm1_kernel(
    const u16* __restrict__ xb, const u16* __restrict__ WgT, const u16* __restrict__ WuT,
    const u16* __restrict__ SgT, const u16* __restrict__ SuT,
    const int* __restrict__ tok, const int* __restrict__ meta, u16* __restrict__ Hbuf)
{
  const int rb = blockIdx.y;
  if (rb >= meta[210]) return;
  const int e = meta[212+rb];
  const u16* __restrict__ Bg = (e < NEXP) ? (WgT + (size_t)e*ID*HD) : SgT;
  const u16* __restrict__ Bu = (e < NEXP) ? (WuT + (size_t)e*ID*HD) : SuT;
  const int n0 = blockIdx.x << 7;
  const int a0 = rb << 7;
  __shared__ u16 smem[24576];                 // 48 KiB: A | G | U tiles (128 x 64 bf16 each)
  u16* sA = smem; u16* sG = smem + 8192; u16* sU = smem + 16384;
  const int tid = threadIdx.x;
  const int wave = tid >> 6, lane = tid & 63;
  const int wr = wave >> 1, wc = wave & 1;
  const int kb = (lane & 7) ^ (lane >> 3);     // swizzled source k-block
  const int sw = (lane & 7) << 3;              // read-side XOR (row&7 == lane&7)
  int trowA[4];
  #pragma unroll
  for (int r=0;r<4;r++){
    int row = (wave*4+r)*8 + (lane>>3);
    int tt = tok[a0 + row];
    trowA[r] = (tt < 0) ? 0 : tt;             // pad rows read row 0 (discarded later)
  }
  f32x4 accG[4][4], accU[4][4];
  const f32x4 zz = {0.f,0.f,0.f,0.f};
  #pragma unroll
  for (int mi=0;mi<4;mi++)
    #pragma unroll
    for (int ni=0;ni<4;ni++){ accG[mi][ni] = zz; accU[mi][ni] = zz; }

  for (int it=0; it<HD/64; ++it){
    const int k0 = it*64;
    #pragma unroll
    for (int r=0;r<4;r++){
      const int chunk = wave*4 + r;
      const int row = chunk*8 + (lane>>3);
      gld16(xb + (size_t)trowA[r]*HD + k0 + kb*8, sA + chunk*512);
      gld16(Bg + (size_t)(n0+row)*HD + k0 + kb*8, sG + chunk*512);
      gld16(Bu + (size_t)(n0+row)*HD + k0 + kb*8, sU + chunk*512);
    }
    __syncthreads();
    #pragma unroll
    for (int ks=0; ks<2; ++ks){
      const int ko = ks*32 + ((lane>>4)<<3);
      const int kx = ko ^ sw;
      bf16x8 av[4];
      #pragma unroll
      for (int mi=0;mi<4;mi++)
        av[mi] = *(const bf16x8*)(sA + (wr*64+mi*16+(lane&15))*64 + kx);
      #pragma unroll
      for (int ni=0;ni<4;ni++){
        bf16x8 gv = *(const bf16x8*)(sG + (wc*64+ni*16+(lane&15))*64 + kx);
        bf16x8 uv = *(const bf16x8*)(sU + (wc*64+ni*16+(lane&15))*64 + kx);
        #pragma unroll
        for (int mi=0;mi<4;mi++){
          accG[mi][ni] = __builtin_amdgcn_mfma_f32_16x16x32_bf16(av[mi], gv, accG[mi][ni], 0,0,0);
          accU[mi][ni] = __builtin_amdgcn_mfma_f32_16x16x32_bf16(av[mi], uv, accU[mi][ni], 0,0,0);
        }
      }
    }
    __syncthreads();
  }
  // epilogue: silu(g)*u -> bf16 tile in LDS -> coalesced store
  u16* hT = smem;                              // 128x128 bf16 = 32 KiB
  #pragma unroll
  for (int mi=0;mi<4;mi++){
    #pragma unroll
    for (int ni=0;ni<4;ni++){
      const int col = wc*64 + ni*16 + (lane&15);
      #pragma unroll
      for (int j=0;j<4;j++){
        const int row = wr*64 + mi*16 + ((lane>>4)<<2) + j;
        const float g = accG[mi][ni][j], u = accU[mi][ni][j];
        const float h = (g / (1.f + __expf(-g))) * u;
        hT[row*128 + col] = f2bf(h);
      }
    }
  }
  __syncthreads();
  #pragma unroll
  for (int r=0;r<8;r++){
    const int o = r*2048 + tid*8;
    const int row = o >> 7, col = o & 127;
    *(u16x8*)(Hbuf + (size_t)(a0+row)*ID + n0 + col) = *(const u16x8*)(hT + o);
  }
}

// ---------------- GEMM2: y = h @ Wd -> bf16 Ybuf (no atomics) ----------------
__global__ __launch_bounds__(256,2) void gemm2_kernel(
    const u16* __restrict__ Hbuf, const u16* __restrict__ WdT, const u16* __restrict__ SdT,
    const int* __restrict__ tok, const int* __restrict__ meta, u16* __restrict__ Ybuf)
{
  const int rb = blockIdx.y;
  if (rb >= meta[210]) return;
  const int e = meta[212+rb];
  const u16* __restrict__ Bd = (e < NEXP) ? (WdT + (size_t)e*HD*ID) : SdT;
  const int n0 = blockIdx.x << 7;
  const int a0 = rb << 7;
  __shared__ u16 smem[16384];                  // 32 KiB: A | B tiles
  u16* sA = smem; u16* sB = smem + 8192;
  const int tid = threadIdx.x;
  const int wave = tid >> 6, lane = tid & 63;
  const int wr = wave >> 1, wc = wave & 1;
  const int kb = (lane & 7) ^ (lane >> 3);     // swizzled source k-block
  const int sw = (lane & 7) << 3;              // read-side XOR
  f32x4 acc[4][4];
  const f32x4 zz = {0.f,0.f,0.f,0.f};
  #pragma unroll
  for (int mi=0;mi<4;mi++)
    #pragma unroll
    for (int ni=0;ni<4;ni++) acc[mi][ni] = zz;

  for (int it=0; it<ID/64; ++it){
    const int k0 = it*64;
    #pragma unroll
    for (int r=0;r<4;r++){
      const int chunk = wave*4 + r;
      const int row = chunk*8 + (lane>>3);
      gld16(Hbuf + (size_t)(a0+row)*ID + k0 + kb*8, sA + chunk*512);
      gld16(Bd   + (size_t)(n0+row)*ID + k0 + kb*8, sB + chunk*512);
    }
    __syncthreads();
    #pragma unroll
    for (int ks=0; ks<2; ++ks){
      const int ko = ks*32 + ((lane>>4)<<3);
      const int kx = ko ^ sw;
      bf16x8 av[4];
      #pragma unroll
      for (int mi=0;mi<4;mi++)
        av[mi] = *(const bf16x8*)(sA + (wr*64+mi*16+(lane&15))*64 + kx);
      #pragma unroll
      for (int ni=0;ni<4;ni++){
        bf16x8 bv = *(const bf16x8*)(sB + (wc*64+ni*16+(lane&15))*64 + kx);
        #pragma unroll
        for (int mi=0;mi<4;mi++)
          acc[mi][ni] = __builtin_amdgcn_mfma_f32_16x16x32_bf16(av[mi], bv, acc[mi][ni], 0,0,0);
      }
    }
    __syncthreads();
  }
  #pragma unroll
  for (int mi=0;mi<4;mi++){
    #pragma unroll
    for (int j=0;j<4;j++){
      const int row = wr*64 + mi*16 + ((lane>>4)<<2) + j;
      const int a = a0 + row;
      if (tok[a] < 0) continue;                // pad rows: skip store
      u16* yrow = Ybuf + (size_t)a*HD + n0 + wc*64 + (lane&15);
      #pragma unroll
      for (int ni=0;ni<4;ni++)
        yrow[ni*16] = f2bf(acc[mi][ni][j]);
    }
  }
}

// ---------------- combine: out[n] = y_shared[n] + w0*y[r0] + w1*y[r1] ----------------
__global__ __launch_bounds__(256) void combine_kernel(
    const u16* __restrict__ Ybuf, const int4* __restrict__ tokinfo,
    const float2* __restrict__ tw, const int* __restrict__ meta,
    float* __restrict__ out)
{
  const int wave = threadIdx.x >> 6, lane = threadIdx.x & 63;
  const int n = blockIdx.x*4 + wave;
  const int4 ti = tokinfo[n];
  const float2 w = tw[n];
  const int r0 = meta[200+ti.x] + ti.z;
  const int r1 = meta[200+ti.y] + ti.w;
  const size_t c = (size_t)lane*8;
  const u16x8 ys = *(const u16x8*)(Ybuf + (size_t)n*HD + c);
  const u16x8 y0 = *(const u16x8*)(Ybuf + (size_t)r0*HD + c);
  const u16x8 y1 = *(const u16x8*)(Ybuf + (size_t)r1*HD + c);
  float4 o0, o1;
  float* o = (float*)&o0;
  #pragma unroll
  for (int j=0;j<8;j++){
    float r = bf2f(ys[j]) + w.x*bf2f(y0[j]) + w.y*bf2f(y1[j]);
    if (j < 4) ((float*)&o0)[j] = r; else ((float*)&o1)[j-4] = r;
  }
  (void)o;
  float4* op = (float4*)(out + (size_t)n*HD + c);
  op[0] = o0; op[1] = o1;
}

extern "C" void kernel_launch(void* const* d_in, const int* in_sizes, int n_in,
                              void* d_out, int out_size, void* d_ws, size_t ws_size,
                              hipStream_t stream)
{
  (void)in_sizes; (void)n_in; (void)out_size;
  if (ws_size < WS_NEED) return;
  const float* x  = (const float*)d_in[0];
  const float* rw = (const float*)d_in[1];
  const float* Wg = (const float*)d_in[2];
  const float* Wu = (const float*)d_in[3];
  const float* Wd = (const float*)d_in[4];
  const float* Sg = (const float*)d_in[5];
  const float* Su = (const float*)d_in[6];
  const float* Sd = (const float*)d_in[7];
  float* out = (float*)d_out;
  char* ws = (char*)d_ws;
  u16*   xb   = (u16*)  (ws + OFF_XB);
  u16*   WgT  = (u16*)  (ws + OFF_WGT);
  u16*   WuT  = (u16*)  (ws + OFF_WUT);
  u16*   WdT  = (u16*)  (ws + OFF_WDT);
  u16*   SgT  = (u16*)  (ws + OFF_SGT);
  u16*   SuT  = (u16*)  (ws + OFF_SUT);
  u16*   SdT  = (u16*)  (ws + OFF_SDT);
  u16*   Hbuf = (u16*)  (ws + OFF_HBUF);
  u16*   Ybuf = (u16*)  (ws + OFF_YB);
  int*   tok  = (int*)  (ws + OFF_TOK);
  float* wgt  = (float*)(ws + OFF_WGTW);
  int4*  ti   = (int4*) (ws + OFF_TI);
  float2* tw  = (float2*)(ws + OFF_TW);
  int*   meta = (int*)  (ws + OFF_META);

  hipMemsetAsync(meta, 0, 512, stream);   // padded cnt[8] (stride-16 ints)

  transpose_convert_kernel<<<13824, 256, 0, stream>>>(Wg,Wu,Wd,Sg,Su,Sd, WgT,WuT,WdT,SgT,SuT,SdT);
  router_kernel<<<NT/RTOK, 256, 0, stream>>>(x, rw, xb, tok, wgt, ti, tw, meta);
  build_lists_kernel<<<1, 256, 0, stream>>>(meta, tok, wgt, ti, tw);
  gemm1_kernel<<<dim3(ID/128, MAXRB), 256, 0, stream>>>(xb, WgT, WuT, SgT, SuT, tok, meta, Hbuf);
  gemm2_kernel<<<dim3(HD/128, MAXRB), 256, 0, stream>>>(Hbuf, WdT, SdT, tok, meta, Ybuf);
  combine_kernel<<<NT/4, 256, 0, stream>>>(Ybuf, ti, tw, meta, out);
}

// Round 11
// 219.774 us; speedup vs baseline: 1.4407x; 1.0032x over previous
//
#include <hip/hip_runtime.h>

typedef unsigned short u16;
typedef u16 u16x8 __attribute__((ext_vector_type(8)));
typedef __bf16 bf16x8 __attribute__((ext_vector_type(8)));
typedef float f32x4 __attribute__((ext_vector_type(4)));

constexpr int NT   = 4096;   // tokens = B*T
constexpr int HD   = 512;    // hidden
constexpr int ID   = 1024;   // inter
constexpr int NEXP = 8;
constexpr int ROWCAP = 13312;   // 4096 shared + 9216 padded routed (104*128)
constexpr int MAXRB  = 104;

// ---- workspace layout (bytes) ----
constexpr size_t OFF_XB   = 0;
constexpr size_t OFF_WGT  = OFF_XB   + (size_t)NT*HD*2;
constexpr size_t OFF_WUT  = OFF_WGT  + (size_t)NEXP*ID*HD*2;
constexpr size_t OFF_WDT  = OFF_WUT  + (size_t)NEXP*ID*HD*2;
constexpr size_t OFF_SGT  = OFF_WDT  + (size_t)NEXP*HD*ID*2;
constexpr size_t OFF_SUT  = OFF_SGT  + (size_t)ID*HD*2;
constexpr size_t OFF_SDT  = OFF_SUT  + (size_t)ID*HD*2;
constexpr size_t OFF_HBUF = OFF_SDT  + (size_t)HD*ID*2;
constexpr size_t OFF_TOK  = OFF_HBUF + (size_t)ROWCAP*ID*2;
constexpr size_t OFF_WGTW = OFF_TOK  + (size_t)ROWCAP*4;
constexpr size_t OFF_TI   = OFF_WGTW + (size_t)ROWCAP*4;
constexpr size_t OFF_TW   = OFF_TI   + (size_t)NT*16;
constexpr size_t OFF_META = OFF_TW   + (size_t)NT*8;
constexpr size_t WS_NEED  = OFF_META + 2048;
// Ybuf (bf16, ROWCAP x HD = 13.6 MB) aliases WgT+WuT (16.8 MB combined).
// RACE AUDIT (round-9 tripwire fix): bf16 Ybuf fits strictly inside WgT+WuT,
// which are dead after gemm1 (stream-ordered before gemm2). gemm2 reads only
// Hbuf/WdT/SdT/tok/meta: no overlap.
constexpr size_t OFF_YB   = OFF_WGT;
static_assert((size_t)ROWCAP*HD*2 <= (size_t)2*NEXP*ID*HD*2, "Ybuf must fit in WgT+WuT");
// meta int layout:
//   [e*16]           e=0..7   : padded expert counters (64B apart -> no shared cache line)
//   [200..208]                : segoff[0..8] (segoff[8] = total padded rows at [208])
//   [210]                     : nrb
//   [212..316)                : rbe (row-block -> expert table)

__device__ __forceinline__ u16 f2bf(float f){
  unsigned int u = __float_as_uint(f);
  u += 0x7fffu + ((u >> 16) & 1u);
  return (u16)(u >> 16);
}
__device__ __forceinline__ float bf2f(u16 v){
  return __uint_as_float(((unsigned int)v) << 16);
}

#define AS1C(p) ((const __attribute__((address_space(1))) void*)(p))
#define AS3(p)  ((__attribute__((address_space(3))) void*)(p))
__device__ __forceinline__ void gld16(const void* g, void* l){
  __builtin_amdgcn_global_load_lds(AS1C(g), AS3(l), 16, 0, 0);
}

// ---------------- weight transpose+convert: fp32 [R][C] -> bf16 [C][R] ----------------
// Round-11 rewrite: 64x64 tiles, float4 reads (16B/lane), u16x8 writes (16B/lane).
// Old version used scalar 4B loads / 2B stores -> ~1 TB/s effective (~100 us, the
// hidden top cost). LDS [64][65] f32: both phases <=2 lanes/bank (free, m136).
__global__ __launch_bounds__(256) void transpose_convert_kernel(
    const float* __restrict__ Wg, const float* __restrict__ Wu, const float* __restrict__ Wd,
    const float* __restrict__ Sg, const float* __restrict__ Su, const float* __restrict__ Sd,
    u16* __restrict__ WgT, u16* __restrict__ WuT, u16* __restrict__ WdT,
    u16* __restrict__ SgT, u16* __restrict__ SuT, u16* __restrict__ SdT)
{
  int b = blockIdx.x;
  const float* src; u16* dst; int R, C, t;
  if (b < 1024)      { int e=b>>7; t=b&127; src=Wg+(size_t)e*HD*ID; dst=WgT+(size_t)e*ID*HD; R=HD; C=ID; }
  else if (b < 2048) { b-=1024; int e=b>>7; t=b&127; src=Wu+(size_t)e*HD*ID; dst=WuT+(size_t)e*ID*HD; R=HD; C=ID; }
  else if (b < 3072) { b-=2048; int e=b>>7; t=b&127; src=Wd+(size_t)e*ID*HD; dst=WdT+(size_t)e*HD*ID; R=ID; C=HD; }
  else if (b < 3200) { t=b-3072; src=Sg; dst=SgT; R=HD; C=ID; }
  else if (b < 3328) { t=b-3200; src=Su; dst=SuT; R=HD; C=ID; }
  else               { t=b-3328; src=Sd; dst=SdT; R=ID; C=HD; }
  const int tc = C >> 6;
  const int r0 = (t / tc) << 6, c0 = (t % tc) << 6;
  __shared__ float tile[64][65];
  const int tid = threadIdx.x;
  const int lr = tid >> 4, lc = (tid & 15) * 4;
  #pragma unroll
  for (int j=0;j<4;j++){
    const int row = lr + j*16;
    const float4 v = *(const float4*)(src + (size_t)(r0+row)*C + c0 + lc);
    tile[row][lc+0]=v.x; tile[row][lc+1]=v.y; tile[row][lc+2]=v.z; tile[row][lc+3]=v.w;
  }
  __syncthreads();
  const int oc = tid >> 3;          // out-row (orig col) 0..31, +32 second pass
  const int rg = (tid & 7) * 8;     // out-col group (orig rows)
  #pragma unroll
  for (int p=0;p<2;p++){
    const int c = oc + p*32;
    u16x8 v;
    #pragma unroll
    for (int i=0;i<8;i++) v[i] = f2bf(tile[rg+i][c]);
    *(u16x8*)(dst + (size_t)(c0+c)*R + r0 + rg) = v;
  }
}

// ---------------- router: per-block aggregated counting ----------------
constexpr int RTOK = 32;   // tokens per block (8 per wave)
__global__ __launch_bounds__(256) void router_kernel(
    const float* __restrict__ x, const float* __restrict__ rw,
    u16* __restrict__ xb, int* __restrict__ tok, float* __restrict__ wgt,
    int4* __restrict__ tokinfo, float2* __restrict__ tw, int* __restrict__ cnt)
{
  const int wave = threadIdx.x >> 6, lane = threadIdx.x & 63;
  __shared__ int h[8];
  __shared__ int basev[8];
  __shared__ int s_e0[RTOK], s_e1[RTOK], s_l0[RTOK], s_l1[RTOK];
  __shared__ float s_w0[RTOK];
  if (threadIdx.x < 8) h[threadIdx.x] = 0;
  __syncthreads();

  #pragma unroll
  for (int t=0; t<RTOK/4; ++t){
    const int slot = wave*(RTOK/4) + t;
    const int n = blockIdx.x*RTOK + slot;
    const float4 xv0 = *(const float4*)(x + (size_t)n*HD + lane*8);
    const float4 xv1 = *(const float4*)(x + (size_t)n*HD + lane*8 + 4);
    u16x8 xs;
    xs[0]=f2bf(xv0.x); xs[1]=f2bf(xv0.y); xs[2]=f2bf(xv0.z); xs[3]=f2bf(xv0.w);
    xs[4]=f2bf(xv1.x); xs[5]=f2bf(xv1.y); xs[6]=f2bf(xv1.z); xs[7]=f2bf(xv1.w);
    *(u16x8*)(xb + (size_t)n*HD + lane*8) = xs;
    const float xa[8] = {xv0.x,xv0.y,xv0.z,xv0.w,xv1.x,xv1.y,xv1.z,xv1.w};
    float p[8] = {0,0,0,0,0,0,0,0};
    const float4* rp = (const float4*)(rw + (size_t)lane*8*NEXP);
    #pragma unroll
    for (int j=0;j<8;j++){
      float4 r0 = rp[j*2], r1 = rp[j*2+1];
      p[0]+=xa[j]*r0.x; p[1]+=xa[j]*r0.y; p[2]+=xa[j]*r0.z; p[3]+=xa[j]*r0.w;
      p[4]+=xa[j]*r1.x; p[5]+=xa[j]*r1.y; p[6]+=xa[j]*r1.z; p[7]+=xa[j]*r1.w;
    }
    #pragma unroll
    for (int m=1;m<64;m<<=1){
      #pragma unroll
      for (int e=0;e<8;e++) p[e] += __shfl_xor(p[e], m, 64);
    }
    if (lane == 0){
      int e0 = 0; float s0 = p[0];
      #pragma unroll
      for (int e=1;e<8;e++) if (p[e] > s0){ s0 = p[e]; e0 = e; }
      int e1 = -1; float s1 = -3.4e38f;
      #pragma unroll
      for (int e=0;e<8;e++) if (e != e0 && p[e] > s1){ s1 = p[e]; e1 = e; }
      s_e0[slot] = e0; s_e1[slot] = e1;
      s_w0[slot] = 1.f / (1.f + expf(s1 - s0));
      s_l0[slot] = atomicAdd(&h[e0], 1);     // LDS atomics: cheap local ranks
      s_l1[slot] = atomicAdd(&h[e1], 1);
    }
  }
  __syncthreads();
  if (threadIdx.x < 8)                        // 8 global atomics/block, 64B-padded counters
    basev[threadIdx.x] = atomicAdd(cnt + threadIdx.x*16, h[threadIdx.x]);
  __syncthreads();
  if (threadIdx.x < RTOK){
    const int slot = threadIdx.x;
    const int n = blockIdx.x*RTOK + slot;
    const int e0 = s_e0[slot], e1 = s_e1[slot];
    const float w0 = s_w0[slot];
    tokinfo[n] = make_int4(e0, e1, basev[e0]+s_l0[slot], basev[e1]+s_l1[slot]);
    tw[n] = make_float2(w0, 1.f - w0);
    tok[n] = n;       // shared segment (rows 0..NT): identity
    wgt[n] = 1.0f;
  }
}

// ---------------- segment offsets, rb->expert table, pad init, scatter ----------------
__global__ __launch_bounds__(256) void build_lists_kernel(
    int* __restrict__ meta, int* __restrict__ tok, float* __restrict__ wgt,
    const int4* __restrict__ tokinfo, const float2* __restrict__ tw)
{
  __shared__ int s_off[9];
  const int t = threadIdx.x;
  if (t == 0){
    int off = NT;
    for (int e=0;e<NEXP;e++){ meta[200+e] = off; off += ((meta[e*16]+127)>>7)<<7; }
    meta[208] = off;
    meta[210] = off >> 7;                      // nrb
    for (int rb=0; rb<32; rb++) meta[212+rb] = 8;   // shared segment
    for (int e=0;e<NEXP;e++){
      int b0 = meta[200+e] >> 7, b1 = meta[201+e] >> 7;
      for (int rb=b0; rb<b1; rb++) meta[212+rb] = e;
    }
    for (int e=0;e<9;e++) s_off[e] = meta[200+e];
  }
  __syncthreads();
  const int end = s_off[8];
  for (int i = NT + t; i < end; i += 256) tok[i] = -1;
  __syncthreads();
  for (int n = t; n < NT; n += 256){
    int4 ti = tokinfo[n];
    float2 w = tw[n];
    int a0 = s_off[ti.x] + ti.z; tok[a0] = n; wgt[a0] = w.x;
    int a1 = s_off[ti.y] + ti.w; tok[a1] = n; wgt[a1] = w.y;
  }
}

// ---------------- GEMM1: h = silu(x@Wg) * (x@Wu), gathered rows, bf16 out ----------------
// T2 LDS swizzle: global source column-block permuted (kb = (lane&7)^(lane>>3)) so the
// linear global_load_lds dest yields LDS[row][col ^ ((row&7)<<3)]; fragment reads XOR back.
__global__ __launch_bounds__(256,2) void gemm1_kernel(
    const u16* __restrict__ xb, const u16* __restrict__ WgT, const u16* __restrict__ WuT,
    const u16* __restrict__ SgT, const u16* __restrict__ SuT,
    const int* __restrict__ tok, const int* __restrict__ meta, u16* __restrict__ Hbuf)
{
  const int rb = blockIdx.y;
  if (rb >= meta[210]) return;
  const int e = meta[212+rb];
  const u16* __restrict__ Bg = (e < NEXP) ? (WgT + (size_t)e*ID*HD) : SgT;
  const u16* __restrict__ Bu = (e < NEXP) ? (WuT + (size_t)e*ID*HD) : SuT;
  const int n0 = blockIdx.x << 7;
  const int a0 = rb << 7;
  __shared__ u16 smem[24576];                 // 48 KiB: A | G | U tiles (128 x 64 bf16 each)
  u16* sA = smem; u16* sG = smem + 8192; u16* sU = smem + 16384;
  const int tid = threadIdx.x;
  const int wave = tid >> 6, lane = tid & 63;
  const int wr = wave >> 1, wc = wave & 1;
  const int kb = (lane & 7) ^ (lane >> 3);     // swizzled source k-block
  const int sw = (lane & 7) << 3;              // read-side XOR (row&7 == lane&7)
  int trowA[4];
  #pragma unroll
  for (int r=0;r<4;r++){
    int row = (wave*4+r)*8 + (lane>>3);
    int tt = tok[a0 + row];
    trowA[r] = (tt < 0) ? 0 : tt;             // pad rows read row 0 (discarded later)
  }
  f32x4 accG[4][4], accU[4][4];
  const f32x4 zz = {0.f,0.f,0.f,0.f};
  #pragma unroll
  for (int mi=0;mi<4;mi++)
    #pragma unroll
    for (int ni=0;ni<4;ni++){ accG[mi][ni] = zz; accU[mi][ni] = zz; }

  for (int it=0; it<HD/64; ++it){
    const int k0 = it*64;
    #pragma unroll
    for (int r=0;r<4;r++){
      const int chunk = wave*4 + r;
      const int row = chunk*8 + (lane>>3);
      gld16(xb + (size_t)trowA[r]*HD + k0 + kb*8, sA + chunk*512);
      gld16(Bg + (size_t)(n0+row)*HD + k0 + kb*8, sG + chunk*512);
      gld16(Bu + (size_t)(n0+row)*HD + k0 + kb*8, sU + chunk*512);
    }
    __syncthreads();
    #pragma unroll
    for (int ks=0; ks<2; ++ks){
      const int ko = ks*32 + ((lane>>4)<<3);
      const int kx = ko ^ sw;
      bf16x8 av[4];
      #pragma unroll
      for (int mi=0;mi<4;mi++)
        av[mi] = *(const bf16x8*)(sA + (wr*64+mi*16+(lane&15))*64 + kx);
      #pragma unroll
      for (int ni=0;ni<4;ni++){
        bf16x8 gv = *(const bf16x8*)(sG + (wc*64+ni*16+(lane&15))*64 + kx);
        bf16x8 uv = *(const bf16x8*)(sU + (wc*64+ni*16+(lane&15))*64 + kx);
        #pragma unroll
        for (int mi=0;mi<4;mi++){
          accG[mi][ni] = __builtin_amdgcn_mfma_f32_16x16x32_bf16(av[mi], gv, accG[mi][ni], 0,0,0);
          accU[mi][ni] = __builtin_amdgcn_mfma_f32_16x16x32_bf16(av[mi], uv, accU[mi][ni], 0,0,0);
        }
      }
    }
    __syncthreads();
  }
  // epilogue: silu(g)*u -> bf16 tile in LDS -> coalesced store
  u16* hT = smem;                              // 128x128 bf16 = 32 KiB
  #pragma unroll
  for (int mi=0;mi<4;mi++){
    #pragma unroll
    for (int ni=0;ni<4;ni++){
      const int col = wc*64 + ni*16 + (lane&15);
      #pragma unroll
      for (int j=0;j<4;j++){
        const int row = wr*64 + mi*16 + ((lane>>4)<<2) + j;
        const float g = accG[mi][ni][j], u = accU[mi][ni][j];
        const float h = (g / (1.f + __expf(-g))) * u;
        hT[row*128 + col] = f2bf(h);
      }
    }
  }
  __syncthreads();
  #pragma unroll
  for (int r=0;r<8;r++){
    const int o = r*2048 + tid*8;
    const int row = o >> 7, col = o & 127;
    *(u16x8*)(Hbuf + (size_t)(a0+row)*ID + n0 + col) = *(const u16x8*)(hT + o);
  }
}

// ---------------- GEMM2: y = h @ Wd -> bf16 Ybuf (no atomics) ----------------
__global__ __launch_bounds__(256,2) void gemm2_kernel(
    const u16* __restrict__ Hbuf, const u16* __restrict__ WdT, const u16* __restrict__ SdT,
    const int* __restrict__ tok, const int* __restrict__ meta, u16* __restrict__ Ybuf)
{
  const int rb = blockIdx.y;
  if (rb >= meta[210]) return;
  const int e = meta[212+rb];
  const u16* __restrict__ Bd = (e < NEXP) ? (WdT + (size_t)e*HD*ID) : SdT;
  const int n0 = blockIdx.x << 7;
  const int a0 = rb << 7;
  __shared__ u16 smem[16384];                  // 32 KiB: A | B tiles
  u16* sA = smem; u16* sB = smem + 8192;
  const int tid = threadIdx.x;
  const int wave = tid >> 6, lane = tid & 63;
  const int wr = wave >> 1, wc = wave & 1;
  const int kb = (lane & 7) ^ (lane >> 3);     // swizzled source k-block
  const int sw = (lane & 7) << 3;              // read-side XOR
  f32x4 acc[4][4];
  const f32x4 zz = {0.f,0.f,0.f,0.f};
  #pragma unroll
  for (int mi=0;mi<4;mi++)
    #pragma unroll
    for (int ni=0;ni<4;ni++) acc[mi][ni] = zz;

  for (int it=0; it<ID/64; ++it){
    const int k0 = it*64;
    #pragma unroll
    for (int r=0;r<4;r++){
      const int chunk = wave*4 + r;
      const int row = chunk*8 + (lane>>3);
      gld16(Hbuf + (size_t)(a0+row)*ID + k0 + kb*8, sA + chunk*512);
      gld16(Bd   + (size_t)(n0+row)*ID + k0 + kb*8, sB + chunk*512);
    }
    __syncthreads();
    #pragma unroll
    for (int ks=0; ks<2; ++ks){
      const int ko = ks*32 + ((lane>>4)<<3);
      const int kx = ko ^ sw;
      bf16x8 av[4];
      #pragma unroll
      for (int mi=0;mi<4;mi++)
        av[mi] = *(const bf16x8*)(sA + (wr*64+mi*16+(lane&15))*64 + kx);
      #pragma unroll
      for (int ni=0;ni<4;ni++){
        bf16x8 bv = *(const bf16x8*)(sB + (wc*64+ni*16+(lane&15))*64 + kx);
        #pragma unroll
        for (int mi=0;mi<4;mi++)
          acc[mi][ni] = __builtin_amdgcn_mfma_f32_16x16x32_bf16(av[mi], bv, acc[mi][ni], 0,0,0);
      }
    }
    __syncthreads();
  }
  #pragma unroll
  for (int mi=0;mi<4;mi++){
    #pragma unroll
    for (int j=0;j<4;j++){
      const int row = wr*64 + mi*16 + ((lane>>4)<<2) + j;
      const int a = a0 + row;
      if (tok[a] < 0) continue;                // pad rows: skip store
      u16* yrow = Ybuf + (size_t)a*HD + n0 + wc*64 + (lane&15);
      #pragma unroll
      for (int ni=0;ni<4;ni++)
        yrow[ni*16] = f2bf(acc[mi][ni][j]);
    }
  }
}

// ---------------- combine: out[n] = y_shared[n] + w0*y[r0] + w1*y[r1] ----------------
__global__ __launch_bounds__(256) void combine_kernel(
    const u16* __restrict__ Ybuf, const int4* __restrict__ tokinfo,
    const float2* __restrict__ tw, const int* __restrict__ meta,
    float* __restrict__ out)
{
  const int wave = threadIdx.x >> 6, lane = threadIdx.x & 63;
  const int n = blockIdx.x*4 + wave;
  const int4 ti = tokinfo[n];
  const float2 w = tw[n];
  const int r0 = meta[200+ti.x] + ti.z;
  const int r1 = meta[200+ti.y] + ti.w;
  const size_t c = (size_t)lane*8;
  const u16x8 ys = *(const u16x8*)(Ybuf + (size_t)n*HD + c);
  const u16x8 y0 = *(const u16x8*)(Ybuf + (size_t)r0*HD + c);
  const u16x8 y1 = *(const u16x8*)(Ybuf + (size_t)r1*HD + c);
  float4 o0, o1;
  #pragma unroll
  for (int j=0;j<8;j++){
    float r = bf2f(ys[j]) + w.x*bf2f(y0[j]) + w.y*bf2f(y1[j]);
    if (j < 4) ((float*)&o0)[j] = r; else ((float*)&o1)[j-4] = r;
  }
  float4* op = (float4*)(out + (size_t)n*HD + c);
  op[0] = o0; op[1] = o1;
}

extern "C" void kernel_launch(void* const* d_in, const int* in_sizes, int n_in,
                              void* d_out, int out_size, void* d_ws, size_t ws_size,
                              hipStream_t stream)
{
  (void)in_sizes; (void)n_in; (void)out_size;
  if (ws_size < WS_NEED) return;
  const float* x  = (const float*)d_in[0];
  const float* rw = (const float*)d_in[1];
  const float* Wg = (const float*)d_in[2];
  const float* Wu = (const float*)d_in[3];
  const float* Wd = (const float*)d_in[4];
  const float* Sg = (const float*)d_in[5];
  const float* Su = (const float*)d_in[6];
  const float* Sd = (const float*)d_in[7];
  float* out = (float*)d_out;
  char* ws = (char*)d_ws;
  u16*   xb   = (u16*)  (ws + OFF_XB);
  u16*   WgT  = (u16*)  (ws + OFF_WGT);
  u16*   WuT  = (u16*)  (ws + OFF_WUT);
  u16*   WdT  = (u16*)  (ws + OFF_WDT);
  u16*   SgT  = (u16*)  (ws + OFF_SGT);
  u16*   SuT  = (u16*)  (ws + OFF_SUT);
  u16*   SdT  = (u16*)  (ws + OFF_SDT);
  u16*   Hbuf = (u16*)  (ws + OFF_HBUF);
  u16*   Ybuf = (u16*)  (ws + OFF_YB);
  int*   tok  = (int*)  (ws + OFF_TOK);
  float* wgt  = (float*)(ws + OFF_WGTW);
  int4*  ti   = (int4*) (ws + OFF_TI);
  float2* tw  = (float2*)(ws + OFF_TW);
  int*   meta = (int*)  (ws + OFF_META);

  hipMemsetAsync(meta, 0, 512, stream);   // padded cnt[8] (stride-16 ints)

  transpose_convert_kernel<<<3456, 256, 0, stream>>>(Wg,Wu,Wd,Sg,Su,Sd, WgT,WuT,WdT,SgT,SuT,SdT);
  router_kernel<<<NT/RTOK, 256, 0, stream>>>(x, rw, xb, tok, wgt, ti, tw, meta);
  build_lists_kernel<<<1, 256, 0, stream>>>(meta, tok, wgt, ti, tw);
  gemm1_kernel<<<dim3(ID/128, MAXRB), 256, 0, stream>>>(xb, WgT, WuT, SgT, SuT, tok, meta, Hbuf);
  gemm2_kernel<<<dim3(HD/128, MAXRB), 256, 0, stream>>>(Hbuf, WdT, SdT, tok, meta, Ybuf);
  combine_kernel<<<NT/4, 256, 0, stream>>>(Ybuf, ti, tw, meta, out);
}